// Round 5
// baseline (1408.827 us; speedup 1.0000x reference)
//
#include <hip/hip_runtime.h>
#include <math.h>

#define Nn 30000
#define RR 3
#define EE 80000

#define SAP 72        // padded LDS row stride (bf16) for lin1's staged tiles
#define EP_LD 68      // per-wave epilogue scratch stride (floats)
#define KBIG 0x40000000

typedef __attribute__((ext_vector_type(8))) short bf16x8;
typedef __attribute__((ext_vector_type(4))) float f32x4;

__device__ __forceinline__ unsigned short f2bf(float f) {
    union { float f; unsigned u; } v; v.f = f;
    unsigned r = v.u + 0x7fff + ((v.u >> 16) & 1);
    return (unsigned short)(r >> 16);
}
__device__ __forceinline__ float bf2f(short h) {
    union { unsigned u; float f; } v;
    v.u = ((unsigned)(unsigned short)h) << 16;
    return v.f;
}
__device__ __forceinline__ float fast_tanh(float x) {
    float e = __expf(2.f * x);
    return 1.f - 2.f / (e + 1.f);
}
__device__ __forceinline__ void unpack8(uint4 u, float* f) {
    union { unsigned u; float f; } a;
    a.u = u.x << 16;          f[0] = a.f;
    a.u = u.x & 0xffff0000u;  f[1] = a.f;
    a.u = u.y << 16;          f[2] = a.f;
    a.u = u.y & 0xffff0000u;  f[3] = a.f;
    a.u = u.z << 16;          f[4] = a.f;
    a.u = u.z & 0xffff0000u;  f[5] = a.f;
    a.u = u.w << 16;          f[6] = a.f;
    a.u = u.w & 0xffff0000u;  f[7] = a.f;
}

// ===========================================================================
// Register-GEMM core for K <= 256 (no LDS staging, no barriers).
// A: bf16 row-major (split at ksplit -> A2). Bt: bf16 [N,K] row-major.
// Block = 128x128 tile, 4 waves each 64x64 (4x4 of 16x16x32 MFMA).
// Fragments loaded straight from global: lane reads A[base+ (lane&15)]
// [c*32 + (lane>>4)*8 ..+7] (16B), same pattern for Bt.
// ===========================================================================
__device__ __forceinline__ void reg_core(
    const short* __restrict__ A, int lda,
    const short* __restrict__ A2, int lda2, int ksplit,
    const short* __restrict__ Bt, int K,
    int M, int m0, int n0, f32x4 (&acc)[4][4])
{
    const int t = threadIdx.x;
    const int lane = t & 63, wave = t >> 6;
    const int wm = (wave >> 1) << 6, wn = (wave & 1) << 6;
    const int fr = lane & 15, quad = lane >> 4;
    const int nchunks = K >> 5;
    for (int c = 0; c < nchunks; c++) {
        int kk = (c << 5) + (quad << 3);
        const short* Ab; int ka, ldax;
        if ((c << 5) < ksplit) { Ab = A;  ka = kk;          ldax = lda;  }
        else                   { Ab = A2; ka = kk - ksplit; ldax = lda2; }
        bf16x8 bf[4], af[4];
        #pragma unroll
        for (int ni = 0; ni < 4; ni++)
            bf[ni] = *(const bf16x8*)(Bt + (size_t)(n0 + wn + ni * 16 + fr) * K + kk);
        #pragma unroll
        for (int mi = 0; mi < 4; mi++) {
            int gr = m0 + wm + mi * 16 + fr;
            bf16x8 va = {0, 0, 0, 0, 0, 0, 0, 0};
            if (gr < M) va = *(const bf16x8*)(Ab + (size_t)gr * ldax + ka);
            af[mi] = va;
        }
        #pragma unroll
        for (int mi = 0; mi < 4; mi++)
            #pragma unroll
            for (int ni = 0; ni < 4; ni++)
                acc[mi][ni] = __builtin_amdgcn_mfma_f32_16x16x32_bf16(
                    af[mi], bf[ni], acc[mi][ni], 0, 0, 0);
    }
}

// General short-K GEMM: C = act(A @ Bt^T + bias); optional f32 C / bf16 Cbf.
__global__ __launch_bounds__(256) void gemm_reg(
    const short* __restrict__ A, int lda,
    const short* __restrict__ A2, int lda2, int ksplit,
    const short* __restrict__ Bt, int K, const float* __restrict__ bias,
    float* __restrict__ C, int ldc, short* __restrict__ Cbf, int ldcbf,
    int M, int act)
{
    __shared__ float eps[4][16 * EP_LD];   // wave-private scratch, never cross-wave
    int m0 = blockIdx.y * 128, n0 = blockIdx.x * 128;
    f32x4 acc[4][4];
    #pragma unroll
    for (int i = 0; i < 4; i++)
        #pragma unroll
        for (int j = 0; j < 4; j++) acc[i][j] = (f32x4){0.f, 0.f, 0.f, 0.f};
    reg_core(A, lda, A2, lda2, ksplit, Bt, K, M, m0, n0, acc);

    const int t = threadIdx.x;
    const int lane = t & 63, wave = t >> 6;
    const int wm = (wave >> 1) << 6, wn = (wave & 1) << 6;
    const int fr = lane & 15, quad = lane >> 4;
    float* ws = eps[wave];
    const int rrow = lane >> 2;
    const int cseg = (lane & 3) << 4;
    #pragma unroll
    for (int mi = 0; mi < 4; mi++) {
        #pragma unroll
        for (int ni = 0; ni < 4; ni++)
            #pragma unroll
            for (int reg = 0; reg < 4; reg++)
                ws[(quad * 4 + reg) * EP_LD + ni * 16 + fr] = acc[mi][ni][reg];
        int gr = m0 + wm + mi * 16 + rrow;
        if (gr >= M) continue;
        int gc = n0 + wn + cseg;
        float vals[16];
        #pragma unroll
        for (int j = 0; j < 16; j++) {
            float v = ws[rrow * EP_LD + cseg + j] + bias[gc + j];
            if (act == 1) v = (v >= 0.f) ? v : 0.01f * v;
            vals[j] = v;
        }
        if (C) {
            float* cp = C + (size_t)gr * ldc + gc;
            #pragma unroll
            for (int j4 = 0; j4 < 4; j4++)
                *(float4*)(cp + j4 * 4) = make_float4(vals[j4 * 4], vals[j4 * 4 + 1],
                                                      vals[j4 * 4 + 2], vals[j4 * 4 + 3]);
        }
        if (Cbf) {
            unsigned pk[8];
            #pragma unroll
            for (int j2 = 0; j2 < 8; j2++)
                pk[j2] = ((unsigned)f2bf(vals[2 * j2 + 1]) << 16) | (unsigned)f2bf(vals[2 * j2]);
            unsigned* bp = (unsigned*)(Cbf + (size_t)gr * ldcbf + gc);
            *(uint4*)bp       = make_uint4(pk[0], pk[1], pk[2], pk[3]);
            *(uint4*)(bp + 4) = make_uint4(pk[4], pk[5], pk[6], pk[7]);
        }
    }
}

// Gate: Z = sigmoid([U_r|h] @ gW + gb); Hm_r = tanh(U_r)*Z + h*(1-Z).
__global__ __launch_bounds__(256) void gate_reg(
    const short* __restrict__ Ubf,   // [N,384] bf16
    const short* __restrict__ Hbf,   // [N,128] bf16
    const short* __restrict__ gWt, const float* __restrict__ gb,
    const float* __restrict__ Uf,    // [N,384] f32
    const float* __restrict__ Hf,    // [N,128] f32
    float* __restrict__ Hm, short* __restrict__ HmBf,   // [N,384]
    int M)
{
    __shared__ float eps[4][16 * EP_LD];
    int r = blockIdx.z;
    int m0 = blockIdx.y * 128;
    f32x4 acc[4][4];
    #pragma unroll
    for (int i = 0; i < 4; i++)
        #pragma unroll
        for (int j = 0; j < 4; j++) acc[i][j] = (f32x4){0.f, 0.f, 0.f, 0.f};
    reg_core(Ubf + r * 128, 384, Hbf, 128, 128, gWt, 256, M, m0, 0, acc);

    const int t = threadIdx.x;
    const int lane = t & 63, wave = t >> 6;
    const int wm = (wave >> 1) << 6, wn = (wave & 1) << 6;
    const int fr = lane & 15, quad = lane >> 4;
    float* ws = eps[wave];
    const int rrow = lane >> 2;
    const int cseg = (lane & 3) << 4;
    #pragma unroll
    for (int mi = 0; mi < 4; mi++) {
        #pragma unroll
        for (int ni = 0; ni < 4; ni++)
            #pragma unroll
            for (int reg = 0; reg < 4; reg++)
                ws[(quad * 4 + reg) * EP_LD + ni * 16 + fr] = acc[mi][ni][reg];
        int gr = m0 + wm + mi * 16 + rrow;
        if (gr >= M) continue;
        int gc = wn + cseg;
        const float* up = Uf + (size_t)gr * 384 + r * 128 + gc;
        const float* hp = Hf + (size_t)gr * 128 + gc;
        float uv[16], hv[16];
        #pragma unroll
        for (int j4 = 0; j4 < 4; j4++) {
            *(float4*)(uv + j4 * 4) = *(const float4*)(up + j4 * 4);
            *(float4*)(hv + j4 * 4) = *(const float4*)(hp + j4 * 4);
        }
        float vals[16];
        #pragma unroll
        for (int j = 0; j < 16; j++) {
            float g = ws[rrow * EP_LD + cseg + j] + gb[gc + j];
            float z = 1.f / (1.f + __expf(-g));
            vals[j] = fast_tanh(uv[j]) * z + hv[j] * (1.f - z);
        }
        float* cp = Hm + (size_t)gr * 384 + r * 128 + gc;
        #pragma unroll
        for (int j4 = 0; j4 < 4; j4++)
            *(float4*)(cp + j4 * 4) = make_float4(vals[j4 * 4], vals[j4 * 4 + 1],
                                                  vals[j4 * 4 + 2], vals[j4 * 4 + 3]);
        unsigned pk[8];
        #pragma unroll
        for (int j2 = 0; j2 < 8; j2++)
            pk[j2] = ((unsigned)f2bf(vals[2 * j2 + 1]) << 16) | (unsigned)f2bf(vals[2 * j2]);
        unsigned* bp = (unsigned*)(HmBf + (size_t)gr * 384 + r * 128 + gc);
        *(uint4*)bp       = make_uint4(pk[0], pk[1], pk[2], pk[3]);
        *(uint4*)(bp + 4) = make_uint4(pk[4], pk[5], pk[6], pk[7]);
    }
}

// Semantic: scores[h*3+r] += sum tanh(Hm[:,r] @ sW1[h] + sb1[h]) . sw2[h]
__global__ __launch_bounds__(256) void semantic_reg(
    const short* __restrict__ HmBf, const short* __restrict__ sW1t,
    const float* __restrict__ sb1, const float* __restrict__ sw2,
    float* __restrict__ scores, int M)
{
    int head = blockIdx.x, r = blockIdx.z;
    int m0 = blockIdx.y * 128, n0 = head * 128;
    f32x4 acc[4][4];
    #pragma unroll
    for (int i = 0; i < 4; i++)
        #pragma unroll
        for (int j = 0; j < 4; j++) acc[i][j] = (f32x4){0.f, 0.f, 0.f, 0.f};
    reg_core(HmBf + r * 128, 384, HmBf + r * 128, 384, KBIG, sW1t, 128, M, m0, n0, acc);

    const int lane = threadIdx.x & 63, wave = threadIdx.x >> 6;
    const int wm = (wave >> 1) << 6, wn = (wave & 1) << 6;
    const int fr = lane & 15, quad = lane >> 4;
    float local = 0.f;
    #pragma unroll
    for (int ni = 0; ni < 4; ni++) {
        int gc = n0 + wn + ni * 16 + fr;
        float b = sb1[gc], w2 = sw2[gc];
        #pragma unroll
        for (int mi = 0; mi < 4; mi++) {
            #pragma unroll
            for (int reg = 0; reg < 4; reg++) {
                int gr = m0 + wm + mi * 16 + quad * 4 + reg;
                if (gr >= M) continue;
                local += fast_tanh(acc[mi][ni][reg] + b) * w2;
            }
        }
    }
    #pragma unroll
    for (int off = 1; off < 64; off <<= 1) local += __shfl_xor(local, off);
    if (lane == 0) atomicAdd(&scores[head * 3 + r], local);
}

// ===========================================================================
// lin1 (K=768): LDS-staged MFMA core (unchanged; trailing k-loop barrier
// makes the As-reuse epilogue safe).
// ===========================================================================
__device__ __forceinline__ void mfma_core(
    const short* __restrict__ A, int lda,
    const short* __restrict__ Bt,
    int M, int K, int m0, int n0,
    short* As, short* Bs, f32x4 (&acc)[4][4])
{
    const int t = threadIdx.x;
    const int srow = t >> 3;
    const int scol = (t & 7) << 3;
    const int lane = t & 63;
    const int wave = t >> 6;
    const int wm = (wave >> 1) << 6;
    const int wn = (wave & 1) << 6;
    const int fr = lane & 15;
    const int quad = lane >> 4;

    for (int k0 = 0; k0 < K; k0 += 64) {
        #pragma unroll
        for (int rr = 0; rr < 4; rr++) {
            int r = srow + rr * 32;
            int gr = m0 + r;
            bf16x8 va = {0, 0, 0, 0, 0, 0, 0, 0};
            if (gr < M) va = *(const bf16x8*)(A + (size_t)gr * lda + k0 + scol);
            *(bf16x8*)(As + r * SAP + scol) = va;
        }
        #pragma unroll
        for (int rr = 0; rr < 4; rr++) {
            int r = srow + rr * 32;
            bf16x8 vb = *(const bf16x8*)(Bt + (size_t)(n0 + r) * K + k0 + scol);
            *(bf16x8*)(Bs + r * SAP + scol) = vb;
        }
        __syncthreads();
        #pragma unroll
        for (int kc = 0; kc < 2; kc++) {
            bf16x8 af[4], bfr[4];
            #pragma unroll
            for (int i = 0; i < 4; i++)
                af[i] = *(const bf16x8*)(As + (wm + i * 16 + fr) * SAP + kc * 32 + quad * 8);
            #pragma unroll
            for (int i = 0; i < 4; i++)
                bfr[i] = *(const bf16x8*)(Bs + (wn + i * 16 + fr) * SAP + kc * 32 + quad * 8);
            #pragma unroll
            for (int mi = 0; mi < 4; mi++)
                #pragma unroll
                for (int ni = 0; ni < 4; ni++)
                    acc[mi][ni] = __builtin_amdgcn_mfma_f32_16x16x32_bf16(
                        af[mi], bfr[ni], acc[mi][ni], 0, 0, 0);
        }
        __syncthreads();
    }
}

__global__ __launch_bounds__(256) void gemm_mfma(
    const short* __restrict__ A, int lda,
    const short* __restrict__ Bt, const float* __restrict__ bias,
    float* __restrict__ C, int ldc, short* __restrict__ Cbf, int ldcbf,
    int M, int K, int act)
{
    __shared__ short As[128 * SAP];
    __shared__ short Bs[128 * SAP];
    f32x4 acc[4][4];
    #pragma unroll
    for (int i = 0; i < 4; i++)
        #pragma unroll
        for (int j = 0; j < 4; j++) acc[i][j] = (f32x4){0.f, 0.f, 0.f, 0.f};
    int m0 = blockIdx.y * 128, n0 = blockIdx.x * 128;
    mfma_core(A, lda, Bt, M, K, m0, n0, As, Bs, acc);

    const int t = threadIdx.x;
    const int lane = t & 63, wave = t >> 6;
    const int wm = (wave >> 1) << 6, wn = (wave & 1) << 6;
    const int fr = lane & 15, quad = lane >> 4;
    float* ws = (float*)As + wave * 16 * EP_LD;   // safe: k-loop ends with barrier
    const int rrow = lane >> 2;
    const int cseg = (lane & 3) << 4;
    #pragma unroll
    for (int mi = 0; mi < 4; mi++) {
        #pragma unroll
        for (int ni = 0; ni < 4; ni++)
            #pragma unroll
            for (int reg = 0; reg < 4; reg++)
                ws[(quad * 4 + reg) * EP_LD + ni * 16 + fr] = acc[mi][ni][reg];
        int gr = m0 + wm + mi * 16 + rrow;
        if (gr >= M) continue;
        int gc = n0 + wn + cseg;
        float vals[16];
        #pragma unroll
        for (int j = 0; j < 16; j++) {
            float v = ws[rrow * EP_LD + cseg + j] + bias[gc + j];
            if (act == 1) v = (v >= 0.f) ? v : 0.01f * v;
            vals[j] = v;
        }
        if (C) {
            float* cp = C + (size_t)gr * ldc + gc;
            #pragma unroll
            for (int j4 = 0; j4 < 4; j4++)
                *(float4*)(cp + j4 * 4) = make_float4(vals[j4 * 4], vals[j4 * 4 + 1],
                                                      vals[j4 * 4 + 2], vals[j4 * 4 + 3]);
        }
        if (Cbf) {
            unsigned pk[8];
            #pragma unroll
            for (int j2 = 0; j2 < 8; j2++)
                pk[j2] = ((unsigned)f2bf(vals[2 * j2 + 1]) << 16) | (unsigned)f2bf(vals[2 * j2]);
            unsigned* bp = (unsigned*)(Cbf + (size_t)gr * ldcbf + gc);
            *(uint4*)bp       = make_uint4(pk[0], pk[1], pk[2], pk[3]);
            *(uint4*)(bp + 4) = make_uint4(pk[4], pk[5], pk[6], pk[7]);
        }
    }
}

__global__ void compute_w_kernel(const float* __restrict__ scores, float* __restrict__ w, float invN)
{
    if (blockIdx.x == 0 && threadIdx.x == 0) {
        float wr[3] = {0.f, 0.f, 0.f};
        for (int h = 0; h < 4; h++) {
            float s0 = scores[h * 3 + 0] * invN;
            float s1 = scores[h * 3 + 1] * invN;
            float s2 = scores[h * 3 + 2] * invN;
            float mx = fmaxf(s0, fmaxf(s1, s2));
            float e0 = __expf(s0 - mx), e1 = __expf(s1 - mx), e2 = __expf(s2 - mx);
            float inv = 1.f / (e0 + e1 + e2);
            wr[0] += 0.25f * e0 * inv;
            wr[1] += 0.25f * e1 * inv;
            wr[2] += 0.25f * e2 * inv;
        }
        w[0] = wr[0]; w[1] = wr[1]; w[2] = wr[2];
    }
}

__global__ void mix_kernel(const float* __restrict__ Hm, const float* __restrict__ w,
                           float* __restrict__ h, short* __restrict__ hbf, int total4)
{
    int i = blockIdx.x * blockDim.x + threadIdx.x;
    if (i >= total4) return;
    int n = i >> 5, c4 = (i & 31) << 2;
    const float* row = Hm + (size_t)n * 384 + c4;
    float4 a = *(const float4*)row;
    float4 b = *(const float4*)(row + 128);
    float4 c = *(const float4*)(row + 256);
    float w0 = w[0], w1 = w[1], w2 = w[2];
    float4 v = make_float4(w0 * a.x + w1 * b.x + w2 * c.x,
                           w0 * a.y + w1 * b.y + w2 * c.y,
                           w0 * a.z + w1 * b.z + w2 * c.z,
                           w0 * a.w + w1 * b.w + w2 * c.w);
    *(float4*)(h + (size_t)n * 128 + c4) = v;
    unsigned p0 = ((unsigned)f2bf(v.y) << 16) | (unsigned)f2bf(v.x);
    unsigned p1 = ((unsigned)f2bf(v.w) << 16) | (unsigned)f2bf(v.z);
    *(uint2*)(hbf + (size_t)n * 128 + c4) = make_uint2(p0, p1);
}

// --------------------------- conversions -----------------------------------
__global__ void convert_bf16_kernel(const float* __restrict__ src, unsigned* __restrict__ dst, int n_pairs)
{
    int i = blockIdx.x * blockDim.x + threadIdx.x;
    if (i >= n_pairs) return;
    float2 f = ((const float2*)src)[i];
    dst[i] = ((unsigned)f2bf(f.y) << 16) | (unsigned)f2bf(f.x);
}

__global__ void prep_global_kernel(const float* __restrict__ lin1_W, const float* __restrict__ lin2_W,
                                   short* __restrict__ lin1Wt, short* __restrict__ lin2Wt)
{
    int id = blockIdx.x * blockDim.x + threadIdx.x;
    if (id < 98304) {
        int n = id / 768, k = id % 768;
        lin1Wt[id] = (short)f2bf(lin1_W[k * 128 + n]);
    } else if (id < 114688) {
        int r = id - 98304;
        int n = r / 128, k = r % 128;
        lin2Wt[r] = (short)f2bf(lin2_W[k * 128 + n]);
    }
}

__global__ void prep_layer_kernel(
    const float* __restrict__ Wq, const float* __restrict__ Wk, const float* __restrict__ Wv,
    const float* __restrict__ Ws, const float* __restrict__ bq, const float* __restrict__ bk,
    const float* __restrict__ bv, const float* __restrict__ gW, const float* __restrict__ sW1,
    short* __restrict__ qkvWt, short* __restrict__ wsT, short* __restrict__ gWt,
    short* __restrict__ sW1t, float* __restrict__ qkvB)
{
    const int S0 = 589824, S1 = 638976, S2 = 671744, S3 = 737280, S4 = 741888;
    int id = blockIdx.x * blockDim.x + threadIdx.x;
    if (id < S0) {
        int r = id / (1536 * 128), rem = id % (1536 * 128);
        int n = rem / 128, k = rem % 128;
        float v;
        if (n < 512)       v = Wq[(size_t)r * 65536 + k * 512 + n];
        else if (n < 1024) v = Wk[(size_t)r * 65536 + k * 512 + (n - 512)];
        else               v = Wv[(size_t)r * 65536 + k * 512 + (n - 1024)];
        qkvWt[id] = (short)f2bf(v);
    } else if (id < S1) {
        int q = id - S0;
        int r = q / 16384, rem = q % 16384;
        int n = rem / 128, k = rem % 128;
        wsT[q] = (short)f2bf(Ws[(size_t)r * 16384 + k * 128 + n]);
    } else if (id < S2) {
        int q = id - S1;
        int n = q / 256, k = q % 256;
        gWt[q] = (short)f2bf(gW[k * 128 + n]);
    } else if (id < S3) {
        int q = id - S2;
        int h = q / 16384, rem = q % 16384;
        int n = rem / 128, k = rem % 128;
        sW1t[q] = (short)f2bf(sW1[(size_t)h * 16384 + k * 128 + n]);
    } else if (id < S4) {
        int q = id - S3;
        int r = q / 1536, n = q % 1536;
        float v;
        if (n < 512)       v = bq[r * 512 + n];
        else if (n < 1024) v = bk[r * 512 + (n - 512)];
        else               v = bv[r * 512 + (n - 1024)];
        qkvB[q] = v;
    }
}

// --------------------------- CSR build (once) ------------------------------
__global__ void zero_i32_kernel(int* __restrict__ p, int n)
{
    int i = blockIdx.x * blockDim.x + threadIdx.x;
    if (i < n) p[i] = 0;
}

__global__ void hist3_kernel(const int* __restrict__ edges, int* __restrict__ cnt3)
{
    int i = blockIdx.x * blockDim.x + threadIdx.x;
    if (i >= 3 * EE) return;
    int r = i / EE, e = i - r * EE;
    int d = edges[(size_t)r * 2 * EE + EE + e];
    atomicAdd(&cnt3[r * Nn + d], 1);
}

__global__ __launch_bounds__(1024) void scan3_kernel(const int* __restrict__ cnt3,
                                                     int* __restrict__ rowptr3)
{
    __shared__ int part[1024];
    const int r = blockIdx.x;
    const int* cnt = cnt3 + r * Nn;
    int* rowptr = rowptr3 + r * (Nn + 1);
    int tid = threadIdx.x;
    int per = (Nn + 1023) >> 10;
    int base = tid * per;
    int s = 0;
    for (int i = 0; i < per; i++) {
        int idx = base + i;
        if (idx < Nn) s += cnt[idx];
    }
    part[tid] = s;
    __syncthreads();
    for (int off = 1; off < 1024; off <<= 1) {
        int val = (tid >= off) ? part[tid - off] : 0;
        __syncthreads();
        part[tid] += val;
        __syncthreads();
    }
    int excl = (tid == 0) ? 0 : part[tid - 1];
    for (int i = 0; i < per; i++) {
        int idx = base + i;
        if (idx < Nn) { rowptr[idx] = excl; excl += cnt[idx]; }
    }
    if (tid == 1023) rowptr[Nn] = part[1023];
}

__global__ void scatter3_kernel(const int* __restrict__ edges,
                                const int* __restrict__ rowptr3, int* __restrict__ fill3,
                                int* __restrict__ col3)
{
    int i = blockIdx.x * blockDim.x + threadIdx.x;
    if (i >= 3 * EE) return;
    int r = i / EE, e = i - r * EE;
    int src = edges[(size_t)r * 2 * EE + e];
    int d   = edges[(size_t)r * 2 * EE + EE + e];
    int pos = rowptr3[r * (Nn + 1) + d] + atomicAdd(&fill3[r * Nn + d], 1);
    col3[r * EE + pos] = src;
}

// --------------------------- attention ------------------------------------
__global__ __launch_bounds__(256) void attn_kernel(
    const short* __restrict__ qkv,
    const int* __restrict__ rowptr, const int* __restrict__ colb,
    float* __restrict__ S, short* __restrict__ Ubf, int N)
{
    int wid = ((blockIdx.x * blockDim.x + threadIdx.x) >> 6);
    int lane = threadIdx.x & 63;
    if (wid >= N) return;
    int n = wid;
    int beg = rowptr[n], end = rowptr[n + 1];

    uint4 qv = ((const uint4*)(qkv + (size_t)n * 1536))[lane];
    float qf[8];
    unpack8(qv, qf);

    float m = -INFINITY, s = 0.f;
    float acc[8] = {0.f, 0.f, 0.f, 0.f, 0.f, 0.f, 0.f, 0.f};
    const float scale = 0.088388347648318447f; // 1/sqrt(128)

    for (int i = beg; i < end; i++) {
        int src = colb[i];
        const short* base = qkv + (size_t)src * 1536;
        uint4 kv4 = ((const uint4*)(base + 512))[lane];
        uint4 vv4 = ((const uint4*)(base + 1024))[lane];
        float kf[8];
        unpack8(kv4, kf);
        float p = qf[0] * kf[0] + qf[1] * kf[1] + qf[2] * kf[2] + qf[3] * kf[3]
                + qf[4] * kf[4] + qf[5] * kf[5] + qf[6] * kf[6] + qf[7] * kf[7];
        p += __shfl_xor(p, 1);
        p += __shfl_xor(p, 2);
        p += __shfl_xor(p, 4);
        p += __shfl_xor(p, 8);
        float l = p * scale;
        float nm = fmaxf(m, l);
        float sc = __expf(m - nm);
        float pe = __expf(l - nm);
        float vf[8];
        unpack8(vv4, vf);
        s = s * sc + pe;
        #pragma unroll
        for (int j = 0; j < 8; j++) acc[j] = acc[j] * sc + pe * vf[j];
        m = nm;
    }

    float inv = (s > 0.f) ? 1.f / s : 0.f;
    #pragma unroll
    for (int j = 0; j < 8; j++) acc[j] *= inv;
    #pragma unroll
    for (int j = 0; j < 8; j++) acc[j] += __shfl_xor(acc[j], 16);
    #pragma unroll
    for (int j = 0; j < 8; j++) acc[j] += __shfl_xor(acc[j], 32);

    if (lane < 16) {
        float* srow = S + (size_t)n * 384 + lane * 8;
        float4 s0 = *(float4*)srow;
        float4 s1 = *(float4*)(srow + 4);
        s0.x += 0.25f * acc[0]; s0.y += 0.25f * acc[1];
        s0.z += 0.25f * acc[2]; s0.w += 0.25f * acc[3];
        s1.x += 0.25f * acc[4]; s1.y += 0.25f * acc[5];
        s1.z += 0.25f * acc[6]; s1.w += 0.25f * acc[7];
        *(float4*)srow       = s0;
        *(float4*)(srow + 4) = s1;
        unsigned p0 = ((unsigned)f2bf(s0.y) << 16) | (unsigned)f2bf(s0.x);
        unsigned p1 = ((unsigned)f2bf(s0.w) << 16) | (unsigned)f2bf(s0.z);
        unsigned p2 = ((unsigned)f2bf(s1.y) << 16) | (unsigned)f2bf(s1.x);
        unsigned p3 = ((unsigned)f2bf(s1.w) << 16) | (unsigned)f2bf(s1.z);
        *(uint4*)(Ubf + (size_t)n * 384 + lane * 8) = make_uint4(p0, p1, p2, p3);
    }
}

// --------------------------- classifier -----------------------------------
__global__ void clf_kernel(const float* __restrict__ t, const float* __restrict__ W,
                           const float* __restrict__ b, float* __restrict__ out, int M)
{
    int n = blockIdx.x * blockDim.x + threadIdx.x;
    if (n >= M) return;
    const float* row = t + (size_t)n * 128;
    float a0 = b[0], a1 = b[1];
    #pragma unroll
    for (int kk = 0; kk < 128; kk++) {
        float a = row[kk];
        a0 += a * W[kk * 2];
        a1 += a * W[kk * 2 + 1];
    }
    out[n * 2] = a0;
    out[n * 2 + 1] = a1;
}

// ---------------------------------------------------------------------------
extern "C" void kernel_launch(void* const* d_in, const int* in_sizes, int n_in,
                              void* d_out, int out_size, void* d_ws, size_t ws_size,
                              hipStream_t stream)
{
    const float* x      = (const float*)d_in[0];
    const int*   edges  = (const int*)d_in[1];
    const float* lin1_W = (const float*)d_in[2];
    const float* lin1_b = (const float*)d_in[3];
    const int L0 = 4, L1 = 17;
    const float* lin2_W = (const float*)d_in[30];
    const float* lin2_b = (const float*)d_in[31];
    const float* clf_W  = (const float*)d_in[32];
    const float* clf_b  = (const float*)d_in[33];
    float* out = (float*)d_out;

    char* w = (char*)d_ws;
    size_t off = 0;
    auto alloc = [&](size_t bytes) { void* p = w + off; off = (off + bytes + 255) & ~(size_t)255; return p; };
    float* h      = (float*)alloc((size_t)Nn * 128 * 4);
    short* h_bf   = (short*)alloc((size_t)Nn * 128 * 2);
    short* qkv_bf = (short*)alloc((size_t)Nn * 1536 * 2);
    short* x_bf   = qkv_bf;   // disjoint liveness union
    float* Sb     = (float*)alloc((size_t)Nn * 384 * 4);
    short* U_bf   = (short*)alloc((size_t)Nn * 384 * 2);
    float* Hm     = (float*)alloc((size_t)Nn * 384 * 4);
    short* Hm_bf  = (short*)alloc((size_t)Nn * 384 * 2);
    short* lin1Wt = (short*)alloc((size_t)98304 * 2);
    short* lin2Wt = (short*)alloc((size_t)16384 * 2);
    short* qkvWt  = (short*)alloc((size_t)2 * 589824 * 2);
    short* wsT    = (short*)alloc((size_t)2 * 49152 * 2);
    short* gWt    = (short*)alloc((size_t)2 * 32768 * 2);
    short* sW1t   = (short*)alloc((size_t)2 * 65536 * 2);
    float* qkvB   = (float*)alloc((size_t)2 * 4608 * 4);
    int* rowptr3  = (int*)alloc((size_t)3 * (Nn + 1) * 4);
    int* cnt3     = (int*)alloc((size_t)3 * Nn * 4);
    int* col3     = (int*)alloc((size_t)3 * EE * 4);
    float* scores = (float*)alloc(12 * 4);
    float* wmix   = (float*)alloc(3 * 4);

    const int MT = (Nn + 127) / 128;    // 235
    dim3 blk(256);

    // ---- prep ----
    {
        int n_pairs = Nn * 768 / 2;
        convert_bf16_kernel<<<(n_pairs + 255) / 256, blk, 0, stream>>>(x, (unsigned*)x_bf, n_pairs);
        prep_global_kernel<<<(114688 + 255) / 256, blk, 0, stream>>>(lin1_W, lin2_W, lin1Wt, lin2Wt);
        for (int l = 0; l < 2; l++) {
            int base = (l == 0) ? L0 : L1;
            prep_layer_kernel<<<(741888 + 255) / 256, blk, 0, stream>>>(
                (const float*)d_in[base + 0], (const float*)d_in[base + 2], (const float*)d_in[base + 4],
                (const float*)d_in[base + 6], (const float*)d_in[base + 1], (const float*)d_in[base + 3],
                (const float*)d_in[base + 5], (const float*)d_in[base + 8], (const float*)d_in[base + 10],
                qkvWt + (size_t)l * 589824, wsT + (size_t)l * 49152, gWt + (size_t)l * 32768,
                sW1t + (size_t)l * 65536, qkvB + (size_t)l * 4608);
        }
        zero_i32_kernel<<<(3 * Nn + 255) / 256, blk, 0, stream>>>(cnt3, 3 * Nn);
        hist3_kernel<<<(3 * EE + 255) / 256, blk, 0, stream>>>(edges, cnt3);
        scan3_kernel<<<3, 1024, 0, stream>>>(cnt3, rowptr3);
        zero_i32_kernel<<<(3 * Nn + 255) / 256, blk, 0, stream>>>(cnt3, 3 * Nn);
        scatter3_kernel<<<(3 * EE + 255) / 256, blk, 0, stream>>>(edges, rowptr3, cnt3, col3);
    }

    // lin1: h = lrelu(x @ lin1_W + b)
    gemm_mfma<<<dim3(1, MT), blk, 0, stream>>>(
        x_bf, 768, lin1Wt, lin1_b, h, 128, h_bf, 128, Nn, 768, 1);

    for (int l = 0; l < 2; l++) {
        int base = (l == 0) ? L0 : L1;
        const float* bs_all = (const float*)d_in[base + 7];
        const float* gb  = (const float*)d_in[base + 9];
        const float* sb1 = (const float*)d_in[base + 11];
        const float* sw2 = (const float*)d_in[base + 12];
        short* lqkvWt = qkvWt + (size_t)l * 589824;
        short* lwsT   = wsT + (size_t)l * 49152;
        short* lgWt   = gWt + (size_t)l * 32768;
        short* lsW1t  = sW1t + (size_t)l * 65536;
        float* lqkvB  = qkvB + (size_t)l * 4608;

        // S = h @ Ws + bs, all 3 relations -> Sb [N,384]
        gemm_reg<<<dim3(3, MT), blk, 0, stream>>>(
            h_bf, 128, h_bf, 128, KBIG, lwsT, 128, bs_all,
            Sb, 384, (short*)nullptr, 0, Nn, 0);

        for (int r = 0; r < RR; r++) {
            gemm_reg<<<dim3(12, MT), blk, 0, stream>>>(
                h_bf, 128, h_bf, 128, KBIG, lqkvWt + (size_t)r * 196608, 128, lqkvB + r * 1536,
                (float*)nullptr, 0, qkv_bf, 1536, Nn, 0);
            attn_kernel<<<(Nn + 3) / 4, blk, 0, stream>>>(
                qkv_bf, rowptr3 + r * (Nn + 1), col3 + r * EE,
                Sb + r * 128, U_bf + r * 128, Nn);
        }

        gate_reg<<<dim3(1, MT, 3), blk, 0, stream>>>(
            U_bf, h_bf, lgWt, gb, Sb, h, Hm, Hm_bf, Nn);

        zero_i32_kernel<<<1, 64, 0, stream>>>((int*)scores, 12);
        semantic_reg<<<dim3(4, MT, 3), blk, 0, stream>>>(Hm_bf, lsW1t, sb1, sw2, scores, Nn);
        compute_w_kernel<<<1, 64, 0, stream>>>(scores, wmix, 1.f / (float)Nn);
        mix_kernel<<<(Nn * 32 + 255) / 256, blk, 0, stream>>>(Hm, wmix, h, h_bf, Nn * 32);
    }

    // lin2 + lrelu -> Sb
    gemm_reg<<<dim3(1, MT), blk, 0, stream>>>(
        h_bf, 128, h_bf, 128, KBIG, lin2Wt, 128, lin2_b,
        Sb, 128, (short*)nullptr, 0, Nn, 1);
    clf_kernel<<<(Nn + 255) / 256, blk, 0, stream>>>(Sb, clf_W, clf_b, out, Nn);
}

// Round 6
// 1038.600 us; speedup vs baseline: 1.3565x; 1.3565x over previous
//
#include <hip/hip_runtime.h>
#include <math.h>

#define Nn 30000
#define RR 3
#define EE 80000
#define MT_M 235      // ceil(Nn/128)

#define SAP 72        // padded LDS row stride (bf16 elems) for staged tiles
#define EP_LD 68      // per-wave epilogue scratch stride (floats)
#define KBIG 0x40000000

typedef __attribute__((ext_vector_type(8))) short bf16x8;
typedef __attribute__((ext_vector_type(4))) float f32x4;

__device__ __forceinline__ unsigned short f2bf(float f) {
    union { float f; unsigned u; } v; v.f = f;
    unsigned r = v.u + 0x7fff + ((v.u >> 16) & 1);
    return (unsigned short)(r >> 16);
}
__device__ __forceinline__ float bf2f(short h) {
    union { unsigned u; float f; } v;
    v.u = ((unsigned)(unsigned short)h) << 16;
    return v.f;
}
__device__ __forceinline__ float fast_tanh(float x) {
    float e = __expf(2.f * x);
    return 1.f - 2.f / (e + 1.f);
}
__device__ __forceinline__ void unpack8(uint4 u, float* f) {
    union { unsigned u; float f; } a;
    a.u = u.x << 16;          f[0] = a.f;
    a.u = u.x & 0xffff0000u;  f[1] = a.f;
    a.u = u.y << 16;          f[2] = a.f;
    a.u = u.y & 0xffff0000u;  f[3] = a.f;
    a.u = u.z << 16;          f[4] = a.f;
    a.u = u.z & 0xffff0000u;  f[5] = a.f;
    a.u = u.w << 16;          f[6] = a.f;
    a.u = u.w & 0xffff0000u;  f[7] = a.f;
}

// ---------------------------------------------------------------------------
// LDS-staged MFMA GEMM core. A: bf16 row-major, K split at ksplit -> A2.
// Bt: bf16 [N,K] row-major. Block tile 128x128, BK=64; 4 waves x (64x64).
// Coalesced staging, ends with a barrier (epilogue may reuse As wave-privately).
// ---------------------------------------------------------------------------
__device__ __forceinline__ void mfma_core(
    const short* __restrict__ A, int lda,
    const short* __restrict__ A2, int lda2, int ksplit,
    const short* __restrict__ Bt,
    int M, int K, int m0, int n0,
    short* As, short* Bs, f32x4 (&acc)[4][4])
{
    const int t = threadIdx.x;
    const int srow = t >> 3;          // 0..31
    const int scol = (t & 7) << 3;    // 0..56 step 8
    const int lane = t & 63;
    const int wave = t >> 6;
    const int wm = (wave >> 1) << 6;
    const int wn = (wave & 1) << 6;
    const int fr = lane & 15;
    const int quad = lane >> 4;

    for (int k0 = 0; k0 < K; k0 += 64) {
        const short* Abase; int kk0, ldax;
        if (k0 < ksplit) { Abase = A;  kk0 = k0;          ldax = lda;  }
        else             { Abase = A2; kk0 = k0 - ksplit; ldax = lda2; }
        #pragma unroll
        for (int rr = 0; rr < 4; rr++) {
            int r = srow + rr * 32;
            int gr = m0 + r;
            bf16x8 va = {0, 0, 0, 0, 0, 0, 0, 0};
            if (gr < M) va = *(const bf16x8*)(Abase + (size_t)gr * ldax + kk0 + scol);
            *(bf16x8*)(As + r * SAP + scol) = va;
        }
        #pragma unroll
        for (int rr = 0; rr < 4; rr++) {
            int r = srow + rr * 32;
            bf16x8 vb = *(const bf16x8*)(Bt + (size_t)(n0 + r) * K + k0 + scol);
            *(bf16x8*)(Bs + r * SAP + scol) = vb;
        }
        __syncthreads();
        #pragma unroll
        for (int kc = 0; kc < 2; kc++) {
            bf16x8 af[4], bfr[4];
            #pragma unroll
            for (int i = 0; i < 4; i++)
                af[i] = *(const bf16x8*)(As + (wm + i * 16 + fr) * SAP + kc * 32 + quad * 8);
            #pragma unroll
            for (int i = 0; i < 4; i++)
                bfr[i] = *(const bf16x8*)(Bs + (wn + i * 16 + fr) * SAP + kc * 32 + quad * 8);
            #pragma unroll
            for (int mi = 0; mi < 4; mi++)
                #pragma unroll
                for (int ni = 0; ni < 4; ni++)
                    acc[mi][ni] = __builtin_amdgcn_mfma_f32_16x16x32_bf16(
                        af[mi], bfr[ni], acc[mi][ni], 0, 0, 0);
        }
        __syncthreads();
    }
}

// General GEMM: C = act(A @ Bt^T + bias). Wave-private LDS repack epilogue.
__global__ __launch_bounds__(256) void gemm_mfma(
    const short* __restrict__ A, int lda,
    const short* __restrict__ A2, int lda2, int ksplit,
    const short* __restrict__ Bt, const float* __restrict__ bias,
    float* __restrict__ C, int ldc, short* __restrict__ Cbf, int ldcbf,
    int M, int K, int act)
{
    __shared__ short As[128 * SAP];
    __shared__ short Bs[128 * SAP];
    f32x4 acc[4][4];
    #pragma unroll
    for (int i = 0; i < 4; i++)
        #pragma unroll
        for (int j = 0; j < 4; j++) acc[i][j] = (f32x4){0.f, 0.f, 0.f, 0.f};
    int m0 = blockIdx.y * 128, n0 = blockIdx.x * 128;
    mfma_core(A, lda, A2, lda2, ksplit, Bt, M, K, m0, n0, As, Bs, acc);

    const int t = threadIdx.x;
    const int lane = t & 63, wave = t >> 6;
    const int wm = (wave >> 1) << 6, wn = (wave & 1) << 6;
    const int fr = lane & 15, quad = lane >> 4;
    float* ws = (float*)As + wave * 16 * EP_LD;   // wave-private (post-barrier)
    const int rrow = lane >> 2;
    const int cseg = (lane & 3) << 4;
    #pragma unroll
    for (int mi = 0; mi < 4; mi++) {
        #pragma unroll
        for (int ni = 0; ni < 4; ni++)
            #pragma unroll
            for (int reg = 0; reg < 4; reg++)
                ws[(quad * 4 + reg) * EP_LD + ni * 16 + fr] = acc[mi][ni][reg];
        int gr = m0 + wm + mi * 16 + rrow;
        if (gr >= M) continue;
        int gc = n0 + wn + cseg;
        float vals[16];
        #pragma unroll
        for (int j = 0; j < 16; j++) {
            float v = ws[rrow * EP_LD + cseg + j] + bias[gc + j];
            if (act == 1) v = (v >= 0.f) ? v : 0.01f * v;
            vals[j] = v;
        }
        if (C) {
            float* cp = C + (size_t)gr * ldc + gc;
            #pragma unroll
            for (int j4 = 0; j4 < 4; j4++)
                *(float4*)(cp + j4 * 4) = make_float4(vals[j4 * 4], vals[j4 * 4 + 1],
                                                      vals[j4 * 4 + 2], vals[j4 * 4 + 3]);
        }
        if (Cbf) {
            unsigned pk[8];
            #pragma unroll
            for (int j2 = 0; j2 < 8; j2++)
                pk[j2] = ((unsigned)f2bf(vals[2 * j2 + 1]) << 16) | (unsigned)f2bf(vals[2 * j2]);
            unsigned* bp = (unsigned*)(Cbf + (size_t)gr * ldcbf + gc);
            *(uint4*)bp       = make_uint4(pk[0], pk[1], pk[2], pk[3]);
            *(uint4*)(bp + 4) = make_uint4(pk[4], pk[5], pk[6], pk[7]);
        }
    }
}

// Gate (z = relation): Z = sigmoid([U_r|h] @ gW + gb); Hm_r = tanh(U_r)*Z + h*(1-Z).
__global__ __launch_bounds__(256) void gate_mfma(
    const short* __restrict__ Ubf,   // [N,384] bf16
    const short* __restrict__ Hbf,   // [N,128] bf16
    const short* __restrict__ gWt, const float* __restrict__ gb,
    const float* __restrict__ Uf,    // [N,384] fp32
    const float* __restrict__ Hf,    // [N,128] fp32
    float* __restrict__ Hm, short* __restrict__ HmBf,   // [N,384]
    int M)
{
    __shared__ short As[128 * SAP];
    __shared__ short Bs[128 * SAP];
    f32x4 acc[4][4];
    #pragma unroll
    for (int i = 0; i < 4; i++)
        #pragma unroll
        for (int j = 0; j < 4; j++) acc[i][j] = (f32x4){0.f, 0.f, 0.f, 0.f};
    int r = blockIdx.z;
    int m0 = blockIdx.y * 128;
    mfma_core(Ubf + r * 128, 384, Hbf, 128, 128, gWt, M, 256, m0, 0, As, Bs, acc);

    const int t = threadIdx.x;
    const int lane = t & 63, wave = t >> 6;
    const int wm = (wave >> 1) << 6, wn = (wave & 1) << 6;
    const int fr = lane & 15, quad = lane >> 4;
    float* ws = (float*)As + wave * 16 * EP_LD;
    const int rrow = lane >> 2;
    const int cseg = (lane & 3) << 4;
    #pragma unroll
    for (int mi = 0; mi < 4; mi++) {
        #pragma unroll
        for (int ni = 0; ni < 4; ni++)
            #pragma unroll
            for (int reg = 0; reg < 4; reg++)
                ws[(quad * 4 + reg) * EP_LD + ni * 16 + fr] = acc[mi][ni][reg];
        int gr = m0 + wm + mi * 16 + rrow;
        if (gr >= M) continue;
        int gc = wn + cseg;
        const float* up = Uf + (size_t)gr * 384 + r * 128 + gc;
        const float* hp = Hf + (size_t)gr * 128 + gc;
        float uv[16], hv[16];
        #pragma unroll
        for (int j4 = 0; j4 < 4; j4++) {
            *(float4*)(uv + j4 * 4) = *(const float4*)(up + j4 * 4);
            *(float4*)(hv + j4 * 4) = *(const float4*)(hp + j4 * 4);
        }
        float vals[16];
        #pragma unroll
        for (int j = 0; j < 16; j++) {
            float g = ws[rrow * EP_LD + cseg + j] + gb[gc + j];
            float z = 1.f / (1.f + __expf(-g));
            vals[j] = fast_tanh(uv[j]) * z + hv[j] * (1.f - z);
        }
        float* cp = Hm + (size_t)gr * 384 + r * 128 + gc;
        #pragma unroll
        for (int j4 = 0; j4 < 4; j4++)
            *(float4*)(cp + j4 * 4) = make_float4(vals[j4 * 4], vals[j4 * 4 + 1],
                                                  vals[j4 * 4 + 2], vals[j4 * 4 + 3]);
        unsigned pk[8];
        #pragma unroll
        for (int j2 = 0; j2 < 8; j2++)
            pk[j2] = ((unsigned)f2bf(vals[2 * j2 + 1]) << 16) | (unsigned)f2bf(vals[2 * j2]);
        unsigned* bp = (unsigned*)(HmBf + (size_t)gr * 384 + r * 128 + gc);
        *(uint4*)bp       = make_uint4(pk[0], pk[1], pk[2], pk[3]);
        *(uint4*)(bp + 4) = make_uint4(pk[4], pk[5], pk[6], pk[7]);
    }
}

// Semantic: partial[z][by] = block sum of tanh(Hm[:,r] @ sW1[h] + sb1).sw2
// NO atomics — plain store per block; reduce12_kernel folds the 235 partials.
__global__ __launch_bounds__(256) void semantic_mfma(
    const short* __restrict__ HmBf, const short* __restrict__ sW1t,
    const float* __restrict__ sb1, const float* __restrict__ sw2,
    float* __restrict__ partial, int M)
{
    __shared__ short As[128 * SAP];
    __shared__ short Bs[128 * SAP];
    __shared__ float red4[4];
    f32x4 acc[4][4];
    #pragma unroll
    for (int i = 0; i < 4; i++)
        #pragma unroll
        for (int j = 0; j < 4; j++) acc[i][j] = (f32x4){0.f, 0.f, 0.f, 0.f};
    int head = blockIdx.x, r = blockIdx.z;
    int m0 = blockIdx.y * 128, n0 = head * 128;
    mfma_core(HmBf + r * 128, 384, HmBf + r * 128, 384, KBIG, sW1t, M, 128, m0, n0, As, Bs, acc);
    const int t = threadIdx.x;
    const int lane = t & 63, wave = t >> 6;
    const int wm = (wave >> 1) << 6, wn = (wave & 1) << 6;
    const int fr = lane & 15, quad = lane >> 4;
    float local = 0.f;
    #pragma unroll
    for (int ni = 0; ni < 4; ni++) {
        int gc = n0 + wn + ni * 16 + fr;
        float b = sb1[gc], w2 = sw2[gc];
        #pragma unroll
        for (int mi = 0; mi < 4; mi++) {
            #pragma unroll
            for (int reg = 0; reg < 4; reg++) {
                int gr = m0 + wm + mi * 16 + quad * 4 + reg;
                if (gr >= M) continue;
                local += fast_tanh(acc[mi][ni][reg] + b) * w2;
            }
        }
    }
    #pragma unroll
    for (int off = 1; off < 64; off <<= 1) local += __shfl_xor(local, off);
    if (lane == 0) red4[wave] = local;
    __syncthreads();
    if (t == 0)
        partial[(head * 3 + r) * MT_M + blockIdx.y] = red4[0] + red4[1] + red4[2] + red4[3];
}

__global__ void reduce12_kernel(const float* __restrict__ partial, float* __restrict__ scores)
{
    int z = blockIdx.x;
    int lane = threadIdx.x;   // 64 threads
    float s = 0.f;
    for (int i = lane; i < MT_M; i += 64) s += partial[z * MT_M + i];
    #pragma unroll
    for (int off = 1; off < 64; off <<= 1) s += __shfl_xor(s, off);
    if (lane == 0) scores[z] = s;
}

__global__ void compute_w_kernel(const float* __restrict__ scores, float* __restrict__ w, float invN)
{
    if (blockIdx.x == 0 && threadIdx.x == 0) {
        float wr[3] = {0.f, 0.f, 0.f};
        for (int h = 0; h < 4; h++) {
            float s0 = scores[h * 3 + 0] * invN;
            float s1 = scores[h * 3 + 1] * invN;
            float s2 = scores[h * 3 + 2] * invN;
            float mx = fmaxf(s0, fmaxf(s1, s2));
            float e0 = __expf(s0 - mx), e1 = __expf(s1 - mx), e2 = __expf(s2 - mx);
            float inv = 1.f / (e0 + e1 + e2);
            wr[0] += 0.25f * e0 * inv;
            wr[1] += 0.25f * e1 * inv;
            wr[2] += 0.25f * e2 * inv;
        }
        w[0] = wr[0]; w[1] = wr[1]; w[2] = wr[2];
    }
}

__global__ void mix_kernel(const float* __restrict__ Hm, const float* __restrict__ w,
                           float* __restrict__ h, short* __restrict__ hbf, int total4)
{
    int i = blockIdx.x * blockDim.x + threadIdx.x;
    if (i >= total4) return;
    int n = i >> 5, c4 = (i & 31) << 2;
    const float* row = Hm + (size_t)n * 384 + c4;
    float4 a = *(const float4*)row;
    float4 b = *(const float4*)(row + 128);
    float4 c = *(const float4*)(row + 256);
    float w0 = w[0], w1 = w[1], w2 = w[2];
    float4 v = make_float4(w0 * a.x + w1 * b.x + w2 * c.x,
                           w0 * a.y + w1 * b.y + w2 * c.y,
                           w0 * a.z + w1 * b.z + w2 * c.z,
                           w0 * a.w + w1 * b.w + w2 * c.w);
    *(float4*)(h + (size_t)n * 128 + c4) = v;
    unsigned p0 = ((unsigned)f2bf(v.y) << 16) | (unsigned)f2bf(v.x);
    unsigned p1 = ((unsigned)f2bf(v.w) << 16) | (unsigned)f2bf(v.z);
    *(uint2*)(hbf + (size_t)n * 128 + c4) = make_uint2(p0, p1);
}

// --------------------------- conversions -----------------------------------
__global__ void convert_bf16_kernel(const float* __restrict__ src, unsigned* __restrict__ dst, int n_pairs)
{
    int i = blockIdx.x * blockDim.x + threadIdx.x;
    if (i >= n_pairs) return;
    float2 f = ((const float2*)src)[i];
    dst[i] = ((unsigned)f2bf(f.y) << 16) | (unsigned)f2bf(f.x);
}

__global__ void prep_global_kernel(const float* __restrict__ lin1_W, const float* __restrict__ lin2_W,
                                   short* __restrict__ lin1Wt, short* __restrict__ lin2Wt)
{
    int id = blockIdx.x * blockDim.x + threadIdx.x;
    if (id < 98304) {
        int n = id / 768, k = id % 768;
        lin1Wt[id] = (short)f2bf(lin1_W[k * 128 + n]);
    } else if (id < 114688) {
        int r = id - 98304;
        int n = r / 128, k = r % 128;
        lin2Wt[r] = (short)f2bf(lin2_W[k * 128 + n]);
    }
}

__global__ void prep_layer_kernel(
    const float* __restrict__ Wq, const float* __restrict__ Wk, const float* __restrict__ Wv,
    const float* __restrict__ Ws, const float* __restrict__ bq, const float* __restrict__ bk,
    const float* __restrict__ bv, const float* __restrict__ gW, const float* __restrict__ sW1,
    short* __restrict__ qkvWt, short* __restrict__ wsT, short* __restrict__ gWt,
    short* __restrict__ sW1t, float* __restrict__ qkvB)
{
    const int S0 = 589824, S1 = 638976, S2 = 671744, S3 = 737280, S4 = 741888;
    int id = blockIdx.x * blockDim.x + threadIdx.x;
    if (id < S0) {
        int r = id / (1536 * 128), rem = id % (1536 * 128);
        int n = rem / 128, k = rem % 128;
        float v;
        if (n < 512)       v = Wq[(size_t)r * 65536 + k * 512 + n];
        else if (n < 1024) v = Wk[(size_t)r * 65536 + k * 512 + (n - 512)];
        else               v = Wv[(size_t)r * 65536 + k * 512 + (n - 1024)];
        qkvWt[id] = (short)f2bf(v);
    } else if (id < S1) {
        int q = id - S0;
        int r = q / 16384, rem = q % 16384;
        int n = rem / 128, k = rem % 128;
        wsT[q] = (short)f2bf(Ws[(size_t)r * 16384 + k * 128 + n]);
    } else if (id < S2) {
        int q = id - S1;
        int n = q / 256, k = q % 256;
        gWt[q] = (short)f2bf(gW[k * 128 + n]);
    } else if (id < S3) {
        int q = id - S2;
        int h = q / 16384, rem = q % 16384;
        int n = rem / 128, k = rem % 128;
        sW1t[q] = (short)f2bf(sW1[(size_t)h * 16384 + k * 128 + n]);
    } else if (id < S4) {
        int q = id - S3;
        int r = q / 1536, n = q % 1536;
        float v;
        if (n < 512)       v = bq[r * 512 + n];
        else if (n < 1024) v = bk[r * 512 + (n - 512)];
        else               v = bv[r * 512 + (n - 1024)];
        qkvB[q] = v;
    }
}

// --------------------------- CSR build (once) ------------------------------
__global__ void zero_i32_kernel(int* __restrict__ p, int n)
{
    int i = blockIdx.x * blockDim.x + threadIdx.x;
    if (i < n) p[i] = 0;
}

__global__ void hist3_kernel(const int* __restrict__ edges, int* __restrict__ cnt3)
{
    int i = blockIdx.x * blockDim.x + threadIdx.x;
    if (i >= 3 * EE) return;
    int r = i / EE, e = i - r * EE;
    int d = edges[(size_t)r * 2 * EE + EE + e];
    atomicAdd(&cnt3[r * Nn + d], 1);
}

__global__ __launch_bounds__(1024) void scan3_kernel(const int* __restrict__ cnt3,
                                                     int* __restrict__ rowptr3)
{
    __shared__ int part[1024];
    const int r = blockIdx.x;
    const int* cnt = cnt3 + r * Nn;
    int* rowptr = rowptr3 + r * (Nn + 1);
    int tid = threadIdx.x;
    int per = (Nn + 1023) >> 10;
    int base = tid * per;
    int s = 0;
    for (int i = 0; i < per; i++) {
        int idx = base + i;
        if (idx < Nn) s += cnt[idx];
    }
    part[tid] = s;
    __syncthreads();
    for (int off = 1; off < 1024; off <<= 1) {
        int val = (tid >= off) ? part[tid - off] : 0;
        __syncthreads();
        part[tid] += val;
        __syncthreads();
    }
    int excl = (tid == 0) ? 0 : part[tid - 1];
    for (int i = 0; i < per; i++) {
        int idx = base + i;
        if (idx < Nn) { rowptr[idx] = excl; excl += cnt[idx]; }
    }
    if (tid == 1023) rowptr[Nn] = part[1023];
}

__global__ void scatter3_kernel(const int* __restrict__ edges,
                                const int* __restrict__ rowptr3, int* __restrict__ fill3,
                                int* __restrict__ col3)
{
    int i = blockIdx.x * blockDim.x + threadIdx.x;
    if (i >= 3 * EE) return;
    int r = i / EE, e = i - r * EE;
    int src = edges[(size_t)r * 2 * EE + e];
    int d   = edges[(size_t)r * 2 * EE + EE + e];
    int pos = rowptr3[r * (Nn + 1) + d] + atomicAdd(&fill3[r * Nn + d], 1);
    col3[r * EE + pos] = src;
}

// --------------------------- attention ------------------------------------
__global__ __launch_bounds__(256) void attn_kernel(
    const short* __restrict__ qkv,
    const int* __restrict__ rowptr, const int* __restrict__ colb,
    float* __restrict__ S, short* __restrict__ Ubf, int N)
{
    int wid = ((blockIdx.x * blockDim.x + threadIdx.x) >> 6);
    int lane = threadIdx.x & 63;
    if (wid >= N) return;
    int n = wid;
    int beg = rowptr[n], end = rowptr[n + 1];

    uint4 qv = ((const uint4*)(qkv + (size_t)n * 1536))[lane];
    float qf[8];
    unpack8(qv, qf);

    float m = -INFINITY, s = 0.f;
    float acc[8] = {0.f, 0.f, 0.f, 0.f, 0.f, 0.f, 0.f, 0.f};
    const float scale = 0.088388347648318447f; // 1/sqrt(128)

    for (int i = beg; i < end; i++) {
        int src = colb[i];
        const short* base = qkv + (size_t)src * 1536;
        uint4 kv4 = ((const uint4*)(base + 512))[lane];
        uint4 vv4 = ((const uint4*)(base + 1024))[lane];
        float kf[8];
        unpack8(kv4, kf);
        float p = qf[0] * kf[0] + qf[1] * kf[1] + qf[2] * kf[2] + qf[3] * kf[3]
                + qf[4] * kf[4] + qf[5] * kf[5] + qf[6] * kf[6] + qf[7] * kf[7];
        p += __shfl_xor(p, 1);
        p += __shfl_xor(p, 2);
        p += __shfl_xor(p, 4);
        p += __shfl_xor(p, 8);
        float l = p * scale;
        float nm = fmaxf(m, l);
        float sc = __expf(m - nm);
        float pe = __expf(l - nm);
        float vf[8];
        unpack8(vv4, vf);
        s = s * sc + pe;
        #pragma unroll
        for (int j = 0; j < 8; j++) acc[j] = acc[j] * sc + pe * vf[j];
        m = nm;
    }

    float inv = (s > 0.f) ? 1.f / s : 0.f;
    #pragma unroll
    for (int j = 0; j < 8; j++) acc[j] *= inv;
    #pragma unroll
    for (int j = 0; j < 8; j++) acc[j] += __shfl_xor(acc[j], 16);
    #pragma unroll
    for (int j = 0; j < 8; j++) acc[j] += __shfl_xor(acc[j], 32);

    if (lane < 16) {
        float* srow = S + (size_t)n * 384 + lane * 8;
        float4 s0 = *(float4*)srow;
        float4 s1 = *(float4*)(srow + 4);
        s0.x += 0.25f * acc[0]; s0.y += 0.25f * acc[1];
        s0.z += 0.25f * acc[2]; s0.w += 0.25f * acc[3];
        s1.x += 0.25f * acc[4]; s1.y += 0.25f * acc[5];
        s1.z += 0.25f * acc[6]; s1.w += 0.25f * acc[7];
        *(float4*)srow       = s0;
        *(float4*)(srow + 4) = s1;
        unsigned p0 = ((unsigned)f2bf(s0.y) << 16) | (unsigned)f2bf(s0.x);
        unsigned p1 = ((unsigned)f2bf(s0.w) << 16) | (unsigned)f2bf(s0.z);
        unsigned p2 = ((unsigned)f2bf(s1.y) << 16) | (unsigned)f2bf(s1.x);
        unsigned p3 = ((unsigned)f2bf(s1.w) << 16) | (unsigned)f2bf(s1.z);
        *(uint4*)(Ubf + (size_t)n * 384 + lane * 8) = make_uint4(p0, p1, p2, p3);
    }
}

// --------------------------- classifier -----------------------------------
__global__ void clf_kernel(const float* __restrict__ t, const float* __restrict__ W,
                           const float* __restrict__ b, float* __restrict__ out, int M)
{
    int n = blockIdx.x * blockDim.x + threadIdx.x;
    if (n >= M) return;
    const float* row = t + (size_t)n * 128;
    float a0 = b[0], a1 = b[1];
    #pragma unroll
    for (int kk = 0; kk < 128; kk++) {
        float a = row[kk];
        a0 += a * W[kk * 2];
        a1 += a * W[kk * 2 + 1];
    }
    out[n * 2] = a0;
    out[n * 2 + 1] = a1;
}

// ---------------------------------------------------------------------------
extern "C" void kernel_launch(void* const* d_in, const int* in_sizes, int n_in,
                              void* d_out, int out_size, void* d_ws, size_t ws_size,
                              hipStream_t stream)
{
    const float* x      = (const float*)d_in[0];
    const int*   edges  = (const int*)d_in[1];
    const float* lin1_W = (const float*)d_in[2];
    const float* lin1_b = (const float*)d_in[3];
    const int L0 = 4, L1 = 17;
    const float* lin2_W = (const float*)d_in[30];
    const float* lin2_b = (const float*)d_in[31];
    const float* clf_W  = (const float*)d_in[32];
    const float* clf_b  = (const float*)d_in[33];
    float* out = (float*)d_out;

    char* w = (char*)d_ws;
    size_t off = 0;
    auto alloc = [&](size_t bytes) { void* p = w + off; off = (off + bytes + 255) & ~(size_t)255; return p; };
    float* h      = (float*)alloc((size_t)Nn * 128 * 4);
    short* h_bf   = (short*)alloc((size_t)Nn * 128 * 2);
    short* qkv_bf = (short*)alloc((size_t)Nn * 1536 * 2);
    short* x_bf   = qkv_bf;   // disjoint liveness union
    float* Sb     = (float*)alloc((size_t)Nn * 384 * 4);
    short* U_bf   = (short*)alloc((size_t)Nn * 384 * 2);
    float* Hm     = (float*)alloc((size_t)Nn * 384 * 4);
    short* Hm_bf  = (short*)alloc((size_t)Nn * 384 * 2);
    short* lin1Wt = (short*)alloc((size_t)98304 * 2);
    short* lin2Wt = (short*)alloc((size_t)16384 * 2);
    short* qkvWt  = (short*)alloc((size_t)2 * 589824 * 2);
    short* wsT    = (short*)alloc((size_t)2 * 49152 * 2);
    short* gWt    = (short*)alloc((size_t)2 * 32768 * 2);
    short* sW1t   = (short*)alloc((size_t)2 * 65536 * 2);
    float* qkvB   = (float*)alloc((size_t)2 * 4608 * 4);
    int* rowptr3  = (int*)alloc((size_t)3 * (Nn + 1) * 4);
    int* cnt3     = (int*)alloc((size_t)3 * Nn * 4);
    int* col3     = (int*)alloc((size_t)3 * EE * 4);
    float* partial = (float*)alloc((size_t)12 * MT_M * 4);
    float* scores = (float*)alloc(12 * 4);
    float* wmix   = (float*)alloc(3 * 4);

    const int MT = MT_M;    // 235
    dim3 blk(256);

    // ---- prep ----
    {
        int n_pairs = Nn * 768 / 2;
        convert_bf16_kernel<<<(n_pairs + 255) / 256, blk, 0, stream>>>(x, (unsigned*)x_bf, n_pairs);
        prep_global_kernel<<<(114688 + 255) / 256, blk, 0, stream>>>(lin1_W, lin2_W, lin1Wt, lin2Wt);
        for (int l = 0; l < 2; l++) {
            int base = (l == 0) ? L0 : L1;
            prep_layer_kernel<<<(741888 + 255) / 256, blk, 0, stream>>>(
                (const float*)d_in[base + 0], (const float*)d_in[base + 2], (const float*)d_in[base + 4],
                (const float*)d_in[base + 6], (const float*)d_in[base + 1], (const float*)d_in[base + 3],
                (const float*)d_in[base + 5], (const float*)d_in[base + 8], (const float*)d_in[base + 10],
                qkvWt + (size_t)l * 589824, wsT + (size_t)l * 49152, gWt + (size_t)l * 32768,
                sW1t + (size_t)l * 65536, qkvB + (size_t)l * 4608);
        }
        zero_i32_kernel<<<(3 * Nn + 255) / 256, blk, 0, stream>>>(cnt3, 3 * Nn);
        hist3_kernel<<<(3 * EE + 255) / 256, blk, 0, stream>>>(edges, cnt3);
        scan3_kernel<<<3, 1024, 0, stream>>>(cnt3, rowptr3);
        zero_i32_kernel<<<(3 * Nn + 255) / 256, blk, 0, stream>>>(cnt3, 3 * Nn);
        scatter3_kernel<<<(3 * EE + 255) / 256, blk, 0, stream>>>(edges, rowptr3, cnt3, col3);
    }

    // lin1: h = lrelu(x @ lin1_W + b)
    gemm_mfma<<<dim3(1, MT), blk, 0, stream>>>(
        x_bf, 768, x_bf, 768, KBIG, lin1Wt, lin1_b, h, 128, h_bf, 128, Nn, 768, 1);

    for (int l = 0; l < 2; l++) {
        int base = (l == 0) ? L0 : L1;
        const float* bs_all = (const float*)d_in[base + 7];
        const float* gb  = (const float*)d_in[base + 9];
        const float* sb1 = (const float*)d_in[base + 11];
        const float* sw2 = (const float*)d_in[base + 12];
        short* lqkvWt = qkvWt + (size_t)l * 589824;
        short* lwsT   = wsT + (size_t)l * 49152;
        short* lgWt   = gWt + (size_t)l * 32768;
        short* lsW1t  = sW1t + (size_t)l * 65536;
        float* lqkvB  = qkvB + (size_t)l * 4608;

        // S = h @ Ws + bs, all 3 relations -> Sb [N,384]
        gemm_mfma<<<dim3(3, MT), blk, 0, stream>>>(
            h_bf, 128, h_bf, 128, KBIG, lwsT, bs_all,
            Sb, 384, (short*)nullptr, 0, Nn, 128, 0);

        for (int r = 0; r < RR; r++) {
            gemm_mfma<<<dim3(12, MT), blk, 0, stream>>>(
                h_bf, 128, h_bf, 128, KBIG, lqkvWt + (size_t)r * 196608, lqkvB + r * 1536,
                (float*)nullptr, 0, qkv_bf, 1536, Nn, 128, 0);
            attn_kernel<<<(Nn + 3) / 4, blk, 0, stream>>>(
                qkv_bf, rowptr3 + r * (Nn + 1), col3 + r * EE,
                Sb + r * 128, U_bf + r * 128, Nn);
        }

        gate_mfma<<<dim3(1, MT, 3), blk, 0, stream>>>(
            U_bf, h_bf, lgWt, gb, Sb, h, Hm, Hm_bf, Nn);

        // semantic attention: partial sums (no atomics) -> reduce -> weights
        semantic_mfma<<<dim3(4, MT, 3), blk, 0, stream>>>(Hm_bf, lsW1t, sb1, sw2, partial, Nn);
        reduce12_kernel<<<12, 64, 0, stream>>>(partial, scores);
        compute_w_kernel<<<1, 64, 0, stream>>>(scores, wmix, 1.f / (float)Nn);
        mix_kernel<<<(Nn * 32 + 255) / 256, blk, 0, stream>>>(Hm, wmix, h, h_bf, Nn * 32);
    }

    // lin2 + lrelu -> Sb
    gemm_mfma<<<dim3(1, MT), blk, 0, stream>>>(
        h_bf, 128, h_bf, 128, KBIG, lin2Wt, lin2_b, Sb, 128, (short*)nullptr, 0, Nn, 128, 1);
    clf_kernel<<<(Nn + 255) / 256, blk, 0, stream>>>(Sb, clf_W, clf_b, out, Nn);
}

// Round 7
// 980.774 us; speedup vs baseline: 1.4364x; 1.0590x over previous
//
#include <hip/hip_runtime.h>
#include <math.h>

#define Nn 30000
#define RR 3
#define EE 80000
#define MT_M 235      // ceil(Nn/128)

#define SAP 72        // padded LDS row stride (bf16 elems) for staged tiles
#define EP_LD 68      // per-wave epilogue scratch stride (floats)
#define KBIG 0x40000000

typedef __attribute__((ext_vector_type(8))) short bf16x8;
typedef __attribute__((ext_vector_type(4))) float f32x4;

__device__ __forceinline__ unsigned short f2bf(float f) {
    union { float f; unsigned u; } v; v.f = f;
    unsigned r = v.u + 0x7fff + ((v.u >> 16) & 1);
    return (unsigned short)(r >> 16);
}
__device__ __forceinline__ float bf2f(short h) {
    union { unsigned u; float f; } v;
    v.u = ((unsigned)(unsigned short)h) << 16;
    return v.f;
}
__device__ __forceinline__ float fast_tanh(float x) {
    float e = __expf(2.f * x);
    return 1.f - 2.f / (e + 1.f);
}
__device__ __forceinline__ void unpack8(uint4 u, float* f) {
    union { unsigned u; float f; } a;
    a.u = u.x << 16;          f[0] = a.f;
    a.u = u.x & 0xffff0000u;  f[1] = a.f;
    a.u = u.y << 16;          f[2] = a.f;
    a.u = u.y & 0xffff0000u;  f[3] = a.f;
    a.u = u.z << 16;          f[4] = a.f;
    a.u = u.z & 0xffff0000u;  f[5] = a.f;
    a.u = u.w << 16;          f[6] = a.f;
    a.u = u.w & 0xffff0000u;  f[7] = a.f;
}

// ---------------------------------------------------------------------------
// LDS-staged MFMA GEMM core (128x128 tile, BK=64, 4 waves x 64x64).
// ---------------------------------------------------------------------------
__device__ __forceinline__ void mfma_core(
    const short* __restrict__ A, int lda,
    const short* __restrict__ A2, int lda2, int ksplit,
    const short* __restrict__ Bt,
    int M, int K, int m0, int n0,
    short* As, short* Bs, f32x4 (&acc)[4][4])
{
    const int t = threadIdx.x;
    const int srow = t >> 3;          // 0..31
    const int scol = (t & 7) << 3;    // 0..56 step 8
    const int lane = t & 63;
    const int wave = t >> 6;
    const int wm = (wave >> 1) << 6;
    const int wn = (wave & 1) << 6;
    const int fr = lane & 15;
    const int quad = lane >> 4;

    for (int k0 = 0; k0 < K; k0 += 64) {
        const short* Abase; int kk0, ldax;
        if (k0 < ksplit) { Abase = A;  kk0 = k0;          ldax = lda;  }
        else             { Abase = A2; kk0 = k0 - ksplit; ldax = lda2; }
        #pragma unroll
        for (int rr = 0; rr < 4; rr++) {
            int r = srow + rr * 32;
            int gr = m0 + r;
            bf16x8 va = {0, 0, 0, 0, 0, 0, 0, 0};
            if (gr < M) va = *(const bf16x8*)(Abase + (size_t)gr * ldax + kk0 + scol);
            *(bf16x8*)(As + r * SAP + scol) = va;
        }
        #pragma unroll
        for (int rr = 0; rr < 4; rr++) {
            int r = srow + rr * 32;
            bf16x8 vb = *(const bf16x8*)(Bt + (size_t)(n0 + r) * K + k0 + scol);
            *(bf16x8*)(Bs + r * SAP + scol) = vb;
        }
        __syncthreads();
        #pragma unroll
        for (int kc = 0; kc < 2; kc++) {
            bf16x8 af[4], bfr[4];
            #pragma unroll
            for (int i = 0; i < 4; i++)
                af[i] = *(const bf16x8*)(As + (wm + i * 16 + fr) * SAP + kc * 32 + quad * 8);
            #pragma unroll
            for (int i = 0; i < 4; i++)
                bfr[i] = *(const bf16x8*)(Bs + (wn + i * 16 + fr) * SAP + kc * 32 + quad * 8);
            #pragma unroll
            for (int mi = 0; mi < 4; mi++)
                #pragma unroll
                for (int ni = 0; ni < 4; ni++)
                    acc[mi][ni] = __builtin_amdgcn_mfma_f32_16x16x32_bf16(
                        af[mi], bfr[ni], acc[mi][ni], 0, 0, 0);
        }
        __syncthreads();
    }
}

// General GEMM: C = act(A @ Bt^T + bias). Wave-private LDS repack epilogue.
__global__ __launch_bounds__(256) void gemm_mfma(
    const short* __restrict__ A, int lda,
    const short* __restrict__ A2, int lda2, int ksplit,
    const short* __restrict__ Bt, const float* __restrict__ bias,
    float* __restrict__ C, int ldc, short* __restrict__ Cbf, int ldcbf,
    int M, int K, int act)
{
    __shared__ short As[128 * SAP];
    __shared__ short Bs[128 * SAP];
    f32x4 acc[4][4];
    #pragma unroll
    for (int i = 0; i < 4; i++)
        #pragma unroll
        for (int j = 0; j < 4; j++) acc[i][j] = (f32x4){0.f, 0.f, 0.f, 0.f};
    int m0 = blockIdx.y * 128, n0 = blockIdx.x * 128;
    mfma_core(A, lda, A2, lda2, ksplit, Bt, M, K, m0, n0, As, Bs, acc);

    const int t = threadIdx.x;
    const int lane = t & 63, wave = t >> 6;
    const int wm = (wave >> 1) << 6, wn = (wave & 1) << 6;
    const int fr = lane & 15, quad = lane >> 4;
    float* ws = (float*)As + wave * 16 * EP_LD;   // wave-private (post-barrier)
    const int rrow = lane >> 2;
    const int cseg = (lane & 3) << 4;
    #pragma unroll
    for (int mi = 0; mi < 4; mi++) {
        #pragma unroll
        for (int ni = 0; ni < 4; ni++)
            #pragma unroll
            for (int reg = 0; reg < 4; reg++)
                ws[(quad * 4 + reg) * EP_LD + ni * 16 + fr] = acc[mi][ni][reg];
        int gr = m0 + wm + mi * 16 + rrow;
        if (gr >= M) continue;
        int gc = n0 + wn + cseg;
        float vals[16];
        #pragma unroll
        for (int j = 0; j < 16; j++) {
            float v = ws[rrow * EP_LD + cseg + j] + bias[gc + j];
            if (act == 1) v = (v >= 0.f) ? v : 0.01f * v;
            vals[j] = v;
        }
        if (C) {
            float* cp = C + (size_t)gr * ldc + gc;
            #pragma unroll
            for (int j4 = 0; j4 < 4; j4++)
                *(float4*)(cp + j4 * 4) = make_float4(vals[j4 * 4], vals[j4 * 4 + 1],
                                                      vals[j4 * 4 + 2], vals[j4 * 4 + 3]);
        }
        if (Cbf) {
            unsigned pk[8];
            #pragma unroll
            for (int j2 = 0; j2 < 8; j2++)
                pk[j2] = ((unsigned)f2bf(vals[2 * j2 + 1]) << 16) | (unsigned)f2bf(vals[2 * j2]);
            unsigned* bp = (unsigned*)(Cbf + (size_t)gr * ldcbf + gc);
            *(uint4*)bp       = make_uint4(pk[0], pk[1], pk[2], pk[3]);
            *(uint4*)(bp + 4) = make_uint4(pk[4], pk[5], pk[6], pk[7]);
        }
    }
}

// Fused q|k|v (3 relations) + Ws GEMM. Wt: [4992][128]; bias [4992].
// bx<36: output -> qkv3[r][gr][ (bx%12)*128 + col ], r=bx/12.
// bx>=36: output -> Ubf[gr*384 + (bx-36)*128 + col].
__global__ __launch_bounds__(256) void gemm_qkvs(
    const short* __restrict__ A,       // h_bf [N,128]
    const short* __restrict__ Wt, const float* __restrict__ bias,
    short* __restrict__ qkv3, short* __restrict__ Ubf, int M)
{
    __shared__ short As[128 * SAP];
    __shared__ short Bs[128 * SAP];
    f32x4 acc[4][4];
    #pragma unroll
    for (int i = 0; i < 4; i++)
        #pragma unroll
        for (int j = 0; j < 4; j++) acc[i][j] = (f32x4){0.f, 0.f, 0.f, 0.f};
    int m0 = blockIdx.y * 128, bx = blockIdx.x, n0 = bx * 128;
    mfma_core(A, 128, A, 128, KBIG, Wt, M, 128, m0, n0, As, Bs, acc);

    const int t = threadIdx.x;
    const int lane = t & 63, wave = t >> 6;
    const int wm = (wave >> 1) << 6, wn = (wave & 1) << 6;
    const int fr = lane & 15, quad = lane >> 4;
    float* ws = (float*)As + wave * 16 * EP_LD;
    const int rrow = lane >> 2;
    const int cseg = (lane & 3) << 4;
    #pragma unroll
    for (int mi = 0; mi < 4; mi++) {
        #pragma unroll
        for (int ni = 0; ni < 4; ni++)
            #pragma unroll
            for (int reg = 0; reg < 4; reg++)
                ws[(quad * 4 + reg) * EP_LD + ni * 16 + fr] = acc[mi][ni][reg];
        int gr = m0 + wm + mi * 16 + rrow;
        if (gr >= M) continue;
        int lc = wn + cseg;               // 0..112 local col start
        float vals[16];
        #pragma unroll
        for (int j = 0; j < 16; j++)
            vals[j] = ws[rrow * EP_LD + cseg + j] + bias[n0 + lc + j];
        unsigned pk[8];
        #pragma unroll
        for (int j2 = 0; j2 < 8; j2++)
            pk[j2] = ((unsigned)f2bf(vals[2 * j2 + 1]) << 16) | (unsigned)f2bf(vals[2 * j2]);
        short* dst;
        if (bx < 36) {
            int r = bx / 12;
            dst = qkv3 + ((size_t)(r * Nn + gr)) * 1536 + (bx - r * 12) * 128 + lc;
        } else {
            dst = Ubf + (size_t)gr * 384 + (bx - 36) * 128 + lc;
        }
        unsigned* bp = (unsigned*)dst;
        *(uint4*)bp       = make_uint4(pk[0], pk[1], pk[2], pk[3]);
        *(uint4*)(bp + 4) = make_uint4(pk[4], pk[5], pk[6], pk[7]);
    }
}

// Gate (z = relation): Z = sigmoid([U_r|h] @ gW + gb); Hm_r = tanh(U_r)*Z + h*(1-Z).
// U read as bf16 (no fp32 U buffer).
__global__ __launch_bounds__(256) void gate_mfma(
    const short* __restrict__ Ubf,   // [N,384] bf16
    const short* __restrict__ Hbf,   // [N,128] bf16
    const short* __restrict__ gWt, const float* __restrict__ gb,
    const float* __restrict__ Hf,    // [N,128] fp32
    float* __restrict__ Hm, short* __restrict__ HmBf,   // [N,384]
    int M)
{
    __shared__ short As[128 * SAP];
    __shared__ short Bs[128 * SAP];
    f32x4 acc[4][4];
    #pragma unroll
    for (int i = 0; i < 4; i++)
        #pragma unroll
        for (int j = 0; j < 4; j++) acc[i][j] = (f32x4){0.f, 0.f, 0.f, 0.f};
    int r = blockIdx.z;
    int m0 = blockIdx.y * 128;
    mfma_core(Ubf + r * 128, 384, Hbf, 128, 128, gWt, M, 256, m0, 0, As, Bs, acc);

    const int t = threadIdx.x;
    const int lane = t & 63, wave = t >> 6;
    const int wm = (wave >> 1) << 6, wn = (wave & 1) << 6;
    const int fr = lane & 15, quad = lane >> 4;
    float* ws = (float*)As + wave * 16 * EP_LD;
    const int rrow = lane >> 2;
    const int cseg = (lane & 3) << 4;
    #pragma unroll
    for (int mi = 0; mi < 4; mi++) {
        #pragma unroll
        for (int ni = 0; ni < 4; ni++)
            #pragma unroll
            for (int reg = 0; reg < 4; reg++)
                ws[(quad * 4 + reg) * EP_LD + ni * 16 + fr] = acc[mi][ni][reg];
        int gr = m0 + wm + mi * 16 + rrow;
        if (gr >= M) continue;
        int gc = wn + cseg;
        const short* up = Ubf + (size_t)gr * 384 + r * 128 + gc;
        const float* hp = Hf + (size_t)gr * 128 + gc;
        float uv[16], hv[16];
        uint4 u0 = *(const uint4*)up;
        uint4 u1 = *(const uint4*)(up + 8);
        unpack8(u0, uv); unpack8(u1, uv + 8);
        #pragma unroll
        for (int j4 = 0; j4 < 4; j4++)
            *(float4*)(hv + j4 * 4) = *(const float4*)(hp + j4 * 4);
        float vals[16];
        #pragma unroll
        for (int j = 0; j < 16; j++) {
            float g = ws[rrow * EP_LD + cseg + j] + gb[gc + j];
            float z = 1.f / (1.f + __expf(-g));
            vals[j] = fast_tanh(uv[j]) * z + hv[j] * (1.f - z);
        }
        float* cp = Hm + (size_t)gr * 384 + r * 128 + gc;
        #pragma unroll
        for (int j4 = 0; j4 < 4; j4++)
            *(float4*)(cp + j4 * 4) = make_float4(vals[j4 * 4], vals[j4 * 4 + 1],
                                                  vals[j4 * 4 + 2], vals[j4 * 4 + 3]);
        unsigned pk[8];
        #pragma unroll
        for (int j2 = 0; j2 < 8; j2++)
            pk[j2] = ((unsigned)f2bf(vals[2 * j2 + 1]) << 16) | (unsigned)f2bf(vals[2 * j2]);
        unsigned* bp = (unsigned*)(HmBf + (size_t)gr * 384 + r * 128 + gc);
        *(uint4*)bp       = make_uint4(pk[0], pk[1], pk[2], pk[3]);
        *(uint4*)(bp + 4) = make_uint4(pk[4], pk[5], pk[6], pk[7]);
    }
}

// Semantic partial sums (no atomics).
__global__ __launch_bounds__(256) void semantic_mfma(
    const short* __restrict__ HmBf, const short* __restrict__ sW1t,
    const float* __restrict__ sb1, const float* __restrict__ sw2,
    float* __restrict__ partial, int M)
{
    __shared__ short As[128 * SAP];
    __shared__ short Bs[128 * SAP];
    __shared__ float red4[4];
    f32x4 acc[4][4];
    #pragma unroll
    for (int i = 0; i < 4; i++)
        #pragma unroll
        for (int j = 0; j < 4; j++) acc[i][j] = (f32x4){0.f, 0.f, 0.f, 0.f};
    int head = blockIdx.x, r = blockIdx.z;
    int m0 = blockIdx.y * 128, n0 = head * 128;
    mfma_core(HmBf + r * 128, 384, HmBf + r * 128, 384, KBIG, sW1t, M, 128, m0, n0, As, Bs, acc);
    const int t = threadIdx.x;
    const int lane = t & 63, wave = t >> 6;
    const int wm = (wave >> 1) << 6, wn = (wave & 1) << 6;
    const int fr = lane & 15, quad = lane >> 4;
    float local = 0.f;
    #pragma unroll
    for (int ni = 0; ni < 4; ni++) {
        int gc = n0 + wn + ni * 16 + fr;
        float b = sb1[gc], w2 = sw2[gc];
        #pragma unroll
        for (int mi = 0; mi < 4; mi++) {
            #pragma unroll
            for (int reg = 0; reg < 4; reg++) {
                int gr = m0 + wm + mi * 16 + quad * 4 + reg;
                if (gr >= M) continue;
                local += fast_tanh(acc[mi][ni][reg] + b) * w2;
            }
        }
    }
    #pragma unroll
    for (int off = 1; off < 64; off <<= 1) local += __shfl_xor(local, off);
    if (lane == 0) red4[wave] = local;
    __syncthreads();
    if (t == 0)
        partial[(head * 3 + r) * MT_M + blockIdx.y] = red4[0] + red4[1] + red4[2] + red4[3];
}

__global__ void reduce12_kernel(const float* __restrict__ partial, float* __restrict__ scores)
{
    int z = blockIdx.x;
    int lane = threadIdx.x;   // 64 threads
    float s = 0.f;
    for (int i = lane; i < MT_M; i += 64) s += partial[z * MT_M + i];
    #pragma unroll
    for (int off = 1; off < 64; off <<= 1) s += __shfl_xor(s, off);
    if (lane == 0) scores[z] = s;
}

__global__ void compute_w_kernel(const float* __restrict__ scores, float* __restrict__ w, float invN)
{
    if (blockIdx.x == 0 && threadIdx.x == 0) {
        float wr[3] = {0.f, 0.f, 0.f};
        for (int h = 0; h < 4; h++) {
            float s0 = scores[h * 3 + 0] * invN;
            float s1 = scores[h * 3 + 1] * invN;
            float s2 = scores[h * 3 + 2] * invN;
            float mx = fmaxf(s0, fmaxf(s1, s2));
            float e0 = __expf(s0 - mx), e1 = __expf(s1 - mx), e2 = __expf(s2 - mx);
            float inv = 1.f / (e0 + e1 + e2);
            wr[0] += 0.25f * e0 * inv;
            wr[1] += 0.25f * e1 * inv;
            wr[2] += 0.25f * e2 * inv;
        }
        w[0] = wr[0]; w[1] = wr[1]; w[2] = wr[2];
    }
}

__global__ void mix_kernel(const float* __restrict__ Hm, const float* __restrict__ w,
                           float* __restrict__ h, short* __restrict__ hbf, int total4)
{
    int i = blockIdx.x * blockDim.x + threadIdx.x;
    if (i >= total4) return;
    int n = i >> 5, c4 = (i & 31) << 2;
    const float* row = Hm + (size_t)n * 384 + c4;
    float4 a = *(const float4*)row;
    float4 b = *(const float4*)(row + 128);
    float4 c = *(const float4*)(row + 256);
    float w0 = w[0], w1 = w[1], w2 = w[2];
    float4 v = make_float4(w0 * a.x + w1 * b.x + w2 * c.x,
                           w0 * a.y + w1 * b.y + w2 * c.y,
                           w0 * a.z + w1 * b.z + w2 * c.z,
                           w0 * a.w + w1 * b.w + w2 * c.w);
    *(float4*)(h + (size_t)n * 128 + c4) = v;
    unsigned p0 = ((unsigned)f2bf(v.y) << 16) | (unsigned)f2bf(v.x);
    unsigned p1 = ((unsigned)f2bf(v.w) << 16) | (unsigned)f2bf(v.z);
    *(uint2*)(hbf + (size_t)n * 128 + c4) = make_uint2(p0, p1);
}

// --------------------------- conversions -----------------------------------
__global__ void convert_bf16_kernel(const float* __restrict__ src, unsigned* __restrict__ dst, int n_pairs)
{
    int i = blockIdx.x * blockDim.x + threadIdx.x;
    if (i >= n_pairs) return;
    float2 f = ((const float2*)src)[i];
    dst[i] = ((unsigned)f2bf(f.y) << 16) | (unsigned)f2bf(f.x);
}

__global__ void prep_global_kernel(const float* __restrict__ lin1_W, const float* __restrict__ lin2_W,
                                   short* __restrict__ lin1Wt, short* __restrict__ lin2Wt)
{
    int id = blockIdx.x * blockDim.x + threadIdx.x;
    if (id < 98304) {
        int n = id / 768, k = id % 768;
        lin1Wt[id] = (short)f2bf(lin1_W[k * 128 + n]);
    } else if (id < 114688) {
        int r = id - 98304;
        int n = r / 128, k = r % 128;
        lin2Wt[r] = (short)f2bf(lin2_W[k * 128 + n]);
    }
}

// Combined per-layer prep: qkvsWt [4992][128] (q|k|v for 3 relations + Ws),
// gWt [128][256], sW1t [512][128], qkvsB [4992].
__global__ void prep_layer_kernel(
    const float* __restrict__ Wq, const float* __restrict__ Wk, const float* __restrict__ Wv,
    const float* __restrict__ Ws, const float* __restrict__ bq, const float* __restrict__ bk,
    const float* __restrict__ bv, const float* __restrict__ bs,
    const float* __restrict__ gW, const float* __restrict__ sW1,
    short* __restrict__ qkvsWt, short* __restrict__ gWt,
    short* __restrict__ sW1t, float* __restrict__ qkvsB)
{
    const int S0 = 638976;             // 4992*128
    const int S1 = S0 + 32768;         // + gW
    const int S2 = S1 + 65536;         // + sW1
    const int S3 = S2 + 4992;          // + bias
    int id = blockIdx.x * blockDim.x + threadIdx.x;
    if (id < S0) {
        int n = id / 128, k = id - n * 128;
        float v;
        if (n < 4608) {
            int r = n / 1536, j = n - r * 1536;
            if (j < 512)       v = Wq[(size_t)r * 65536 + k * 512 + j];
            else if (j < 1024) v = Wk[(size_t)r * 65536 + k * 512 + (j - 512)];
            else               v = Wv[(size_t)r * 65536 + k * 512 + (j - 1024)];
        } else {
            int m = n - 4608;
            int r = m / 128, c = m - r * 128;
            v = Ws[(size_t)r * 16384 + k * 128 + c];
        }
        qkvsWt[id] = (short)f2bf(v);
    } else if (id < S1) {
        int q = id - S0;
        int n = q / 256, k = q - n * 256;
        gWt[q] = (short)f2bf(gW[k * 128 + n]);
    } else if (id < S2) {
        int q = id - S1;
        int h = q / 16384, rem = q - h * 16384;
        int n = rem / 128, k = rem - n * 128;
        sW1t[q] = (short)f2bf(sW1[(size_t)h * 16384 + k * 128 + n]);
    } else if (id < S3) {
        int q = id - S2;
        float v;
        if (q < 4608) {
            int r = q / 1536, j = q - r * 1536;
            if (j < 512)       v = bq[r * 512 + j];
            else if (j < 1024) v = bk[r * 512 + (j - 512)];
            else               v = bv[r * 512 + (j - 1024)];
        } else {
            v = bs[q - 4608];
        }
        qkvsB[q] = v;
    }
}

// --------------------------- CSR build (once) ------------------------------
__global__ void zero_i32_kernel(int* __restrict__ p, int n)
{
    int i = blockIdx.x * blockDim.x + threadIdx.x;
    if (i < n) p[i] = 0;
}

__global__ void hist3_kernel(const int* __restrict__ edges, int* __restrict__ cnt3)
{
    int i = blockIdx.x * blockDim.x + threadIdx.x;
    if (i >= 3 * EE) return;
    int r = i / EE, e = i - r * EE;
    int d = edges[(size_t)r * 2 * EE + EE + e];
    atomicAdd(&cnt3[r * Nn + d], 1);
}

__global__ __launch_bounds__(1024) void scan3_kernel(const int* __restrict__ cnt3,
                                                     int* __restrict__ rowptr3)
{
    __shared__ int part[1024];
    const int r = blockIdx.x;
    const int* cnt = cnt3 + r * Nn;
    int* rowptr = rowptr3 + r * (Nn + 1);
    int tid = threadIdx.x;
    int per = (Nn + 1023) >> 10;
    int base = tid * per;
    int s = 0;
    for (int i = 0; i < per; i++) {
        int idx = base + i;
        if (idx < Nn) s += cnt[idx];
    }
    part[tid] = s;
    __syncthreads();
    for (int off = 1; off < 1024; off <<= 1) {
        int val = (tid >= off) ? part[tid - off] : 0;
        __syncthreads();
        part[tid] += val;
        __syncthreads();
    }
    int excl = (tid == 0) ? 0 : part[tid - 1];
    for (int i = 0; i < per; i++) {
        int idx = base + i;
        if (idx < Nn) { rowptr[idx] = excl; excl += cnt[idx]; }
    }
    if (tid == 1023) rowptr[Nn] = part[1023];
}

__global__ void scatter3_kernel(const int* __restrict__ edges,
                                const int* __restrict__ rowptr3, int* __restrict__ fill3,
                                int* __restrict__ col3)
{
    int i = blockIdx.x * blockDim.x + threadIdx.x;
    if (i >= 3 * EE) return;
    int r = i / EE, e = i - r * EE;
    int src = edges[(size_t)r * 2 * EE + e];
    int d   = edges[(size_t)r * 2 * EE + EE + e];
    int pos = rowptr3[r * (Nn + 1) + d] + atomicAdd(&fill3[r * Nn + d], 1);
    col3[r * EE + pos] = src;
}

// --------------------------- attention (all 3 relations) -------------------
// One wave per (dst,relation). qkv3: [3][N][1536]. U in/out: bf16 [N,384].
__global__ __launch_bounds__(256) void attn_kernel(
    const short* __restrict__ qkv3,
    const int* __restrict__ rowptr3, const int* __restrict__ col3,
    short* __restrict__ Ubf)
{
    int wid = ((blockIdx.x * blockDim.x + threadIdx.x) >> 6);
    int lane = threadIdx.x & 63;
    if (wid >= 3 * Nn) return;
    int r = wid / Nn, n = wid - r * Nn;
    const short* qkv = qkv3 + (size_t)r * Nn * 1536;
    const int* rowptr = rowptr3 + r * (Nn + 1);
    const int* colb = col3 + r * EE;
    int beg = rowptr[n], end = rowptr[n + 1];

    uint4 qv = ((const uint4*)(qkv + (size_t)n * 1536))[lane];
    float qf[8];
    unpack8(qv, qf);

    float m = -INFINITY, s = 0.f;
    float acc[8] = {0.f, 0.f, 0.f, 0.f, 0.f, 0.f, 0.f, 0.f};
    const float scale = 0.088388347648318447f; // 1/sqrt(128)

    for (int i = beg; i < end; i++) {
        int src = colb[i];
        const short* base = qkv + (size_t)src * 1536;
        uint4 kv4 = ((const uint4*)(base + 512))[lane];
        uint4 vv4 = ((const uint4*)(base + 1024))[lane];
        float kf[8];
        unpack8(kv4, kf);
        float p = qf[0] * kf[0] + qf[1] * kf[1] + qf[2] * kf[2] + qf[3] * kf[3]
                + qf[4] * kf[4] + qf[5] * kf[5] + qf[6] * kf[6] + qf[7] * kf[7];
        p += __shfl_xor(p, 1);
        p += __shfl_xor(p, 2);
        p += __shfl_xor(p, 4);
        p += __shfl_xor(p, 8);
        float l = p * scale;
        float nm = fmaxf(m, l);
        float sc = __expf(m - nm);
        float pe = __expf(l - nm);
        float vf[8];
        unpack8(vv4, vf);
        s = s * sc + pe;
        #pragma unroll
        for (int j = 0; j < 8; j++) acc[j] = acc[j] * sc + pe * vf[j];
        m = nm;
    }

    float inv = (s > 0.f) ? 1.f / s : 0.f;
    #pragma unroll
    for (int j = 0; j < 8; j++) acc[j] *= inv;
    #pragma unroll
    for (int j = 0; j < 8; j++) acc[j] += __shfl_xor(acc[j], 16);
    #pragma unroll
    for (int j = 0; j < 8; j++) acc[j] += __shfl_xor(acc[j], 32);

    if (lane < 16) {
        short* urow = Ubf + (size_t)n * 384 + r * 128 + lane * 8;
        uint4 old = *(uint4*)urow;
        float sv[8];
        unpack8(old, sv);
        #pragma unroll
        for (int j = 0; j < 8; j++) sv[j] += 0.25f * acc[j];
        unsigned p0 = ((unsigned)f2bf(sv[1]) << 16) | (unsigned)f2bf(sv[0]);
        unsigned p1 = ((unsigned)f2bf(sv[3]) << 16) | (unsigned)f2bf(sv[2]);
        unsigned p2 = ((unsigned)f2bf(sv[5]) << 16) | (unsigned)f2bf(sv[4]);
        unsigned p3 = ((unsigned)f2bf(sv[7]) << 16) | (unsigned)f2bf(sv[6]);
        *(uint4*)urow = make_uint4(p0, p1, p2, p3);
    }
}

// --------------------------- classifier -----------------------------------
__global__ void clf_kernel(const float* __restrict__ t, const float* __restrict__ W,
                           const float* __restrict__ b, float* __restrict__ out, int M)
{
    int n = blockIdx.x * blockDim.x + threadIdx.x;
    if (n >= M) return;
    const float* row = t + (size_t)n * 128;
    float a0 = b[0], a1 = b[1];
    #pragma unroll
    for (int kk = 0; kk < 128; kk++) {
        float a = row[kk];
        a0 += a * W[kk * 2];
        a1 += a * W[kk * 2 + 1];
    }
    out[n * 2] = a0;
    out[n * 2 + 1] = a1;
}

// ---------------------------------------------------------------------------
extern "C" void kernel_launch(void* const* d_in, const int* in_sizes, int n_in,
                              void* d_out, int out_size, void* d_ws, size_t ws_size,
                              hipStream_t stream)
{
    const float* x      = (const float*)d_in[0];
    const int*   edges  = (const int*)d_in[1];
    const float* lin1_W = (const float*)d_in[2];
    const float* lin1_b = (const float*)d_in[3];
    const int L0 = 4, L1 = 17;
    const float* lin2_W = (const float*)d_in[30];
    const float* lin2_b = (const float*)d_in[31];
    const float* clf_W  = (const float*)d_in[32];
    const float* clf_b  = (const float*)d_in[33];
    float* out = (float*)d_out;

    char* w = (char*)d_ws;
    size_t off = 0;
    auto alloc = [&](size_t bytes) { void* p = w + off; off = (off + bytes + 255) & ~(size_t)255; return p; };
    float* h      = (float*)alloc((size_t)Nn * 128 * 4);     // 15.4 MB
    short* h_bf   = (short*)alloc((size_t)Nn * 128 * 2);     //  7.7 MB
    short* U_bf   = (short*)alloc((size_t)Nn * 384 * 2);     // 23.0 MB
    // BIG union region (276.5 MB): qkv3 [3][N][1536] bf16  <->  x_bf [N,768] bf16
    //                              <->  Hm [N,384] f32 + Hm_bf [N,384] bf16
    char* BIG     = (char*)alloc((size_t)3 * Nn * 1536 * 2);
    short* qkv3   = (short*)BIG;
    short* x_bf   = (short*)BIG;
    float* Hm     = (float*)BIG;
    short* Hm_bf  = (short*)(BIG + (size_t)Nn * 384 * 4);
    float* lin2o  = (float*)BIG;                              // lin2 out (post layer-2)
    short* lin1Wt = (short*)alloc((size_t)98304 * 2);
    short* lin2Wt = (short*)alloc((size_t)16384 * 2);
    short* qkvsWt = (short*)alloc((size_t)2 * 638976 * 2);
    short* gWt    = (short*)alloc((size_t)2 * 32768 * 2);
    short* sW1t   = (short*)alloc((size_t)2 * 65536 * 2);
    float* qkvsB  = (float*)alloc((size_t)2 * 4992 * 4);
    int* rowptr3  = (int*)alloc((size_t)3 * (Nn + 1) * 4);
    int* cnt3     = (int*)alloc((size_t)3 * Nn * 4);
    int* col3     = (int*)alloc((size_t)3 * EE * 4);
    float* partial = (float*)alloc((size_t)12 * MT_M * 4);
    float* scores = (float*)alloc(12 * 4);
    float* wmix   = (float*)alloc(3 * 4);

    const int MT = MT_M;    // 235
    dim3 blk(256);

    // ---- prep ----
    {
        int n_pairs = Nn * 768 / 2;
        convert_bf16_kernel<<<(n_pairs + 255) / 256, blk, 0, stream>>>(x, (unsigned*)x_bf, n_pairs);
        prep_global_kernel<<<(114688 + 255) / 256, blk, 0, stream>>>(lin1_W, lin2_W, lin1Wt, lin2Wt);
        for (int l = 0; l < 2; l++) {
            int base = (l == 0) ? L0 : L1;
            prep_layer_kernel<<<(742272 + 255) / 256, blk, 0, stream>>>(
                (const float*)d_in[base + 0], (const float*)d_in[base + 2], (const float*)d_in[base + 4],
                (const float*)d_in[base + 6], (const float*)d_in[base + 1], (const float*)d_in[base + 3],
                (const float*)d_in[base + 5], (const float*)d_in[base + 7],
                (const float*)d_in[base + 8], (const float*)d_in[base + 10],
                qkvsWt + (size_t)l * 638976, gWt + (size_t)l * 32768,
                sW1t + (size_t)l * 65536, qkvsB + (size_t)l * 4992);
        }
        zero_i32_kernel<<<(3 * Nn + 255) / 256, blk, 0, stream>>>(cnt3, 3 * Nn);
        hist3_kernel<<<(3 * EE + 255) / 256, blk, 0, stream>>>(edges, cnt3);
        scan3_kernel<<<3, 1024, 0, stream>>>(cnt3, rowptr3);
        zero_i32_kernel<<<(3 * Nn + 255) / 256, blk, 0, stream>>>(cnt3, 3 * Nn);
        scatter3_kernel<<<(3 * EE + 255) / 256, blk, 0, stream>>>(edges, rowptr3, cnt3, col3);
    }

    // lin1: h = lrelu(x @ lin1_W + b)   (x_bf in BIG; done before qkv overwrites)
    gemm_mfma<<<dim3(1, MT), blk, 0, stream>>>(
        x_bf, 768, x_bf, 768, KBIG, lin1Wt, lin1_b, h, 128, h_bf, 128, Nn, 768, 1);

    for (int l = 0; l < 2; l++) {
        int base = (l == 0) ? L0 : L1;
        const float* gb  = (const float*)d_in[base + 9];
        const float* sb1 = (const float*)d_in[base + 11];
        const float* sw2 = (const float*)d_in[base + 12];
        short* lqkvsWt = qkvsWt + (size_t)l * 638976;
        short* lgWt    = gWt + (size_t)l * 32768;
        short* lsW1t   = sW1t + (size_t)l * 65536;
        float* lqkvsB  = qkvsB + (size_t)l * 4992;

        // fused q|k|v (3 relations) + Ws -> qkv3 + U_bf
        gemm_qkvs<<<dim3(39, MT), blk, 0, stream>>>(
            h_bf, lqkvsWt, lqkvsB, qkv3, U_bf, Nn);

        // attention, all 3 relations: U += mean-head agg (in place, bf16)
        attn_kernel<<<(3 * Nn + 3) / 4, blk, 0, stream>>>(qkv3, rowptr3, col3, U_bf);

        // gate + combine (3 relations) -> Hm (fp32 + bf16)   [qkv3 dead now]
        gate_mfma<<<dim3(1, MT, 3), blk, 0, stream>>>(
            U_bf, h_bf, lgWt, gb, h, Hm, Hm_bf, Nn);

        // semantic attention
        semantic_mfma<<<dim3(4, MT, 3), blk, 0, stream>>>(Hm_bf, lsW1t, sb1, sw2, partial, Nn);
        reduce12_kernel<<<12, 64, 0, stream>>>(partial, scores);
        compute_w_kernel<<<1, 64, 0, stream>>>(scores, wmix, 1.f / (float)Nn);
        mix_kernel<<<(Nn * 32 + 255) / 256, blk, 0, stream>>>(Hm, wmix, h, h_bf, Nn * 32);
    }

    // lin2 + lrelu -> lin2o (BIG region, Hm dead after mix)
    gemm_mfma<<<dim3(1, MT), blk, 0, stream>>>(
        h_bf, 128, h_bf, 128, KBIG, lin2Wt, lin2_b, lin2o, 128, (short*)nullptr, 0, Nn, 128, 1);
    clf_kernel<<<(Nn + 255) / 256, blk, 0, stream>>>(lin2o, clf_W, clf_b, out, Nn);
}